// Round 5
// baseline (1562.037 us; speedup 1.0000x reference)
//
#include <hip/hip_runtime.h>
#include <math.h>

// H=512, heads=8, dh=64, L=2, FF=2048, B=16, Fh=5, Tmem=10, Nobj=20, P=380.
#define HD 512
#define FFD 2048
#define FH 5
#define TM 10
#define NO 20
#define NP 380
#define PRED_N 790400   // 16*5*380*26

typedef short bf16x8 __attribute__((ext_vector_type(8)));
typedef float floatx4 __attribute__((ext_vector_type(4)));

__device__ __forceinline__ float gelu_f(float v) {
    return 0.5f * v * (1.0f + erff(v * 0.70710678118654752440f));
}
__device__ __forceinline__ unsigned short f2bf(float x) {
    unsigned int u = __float_as_uint(x);
    u = (u + 0x7FFFu + ((u >> 16) & 1u)) >> 16;   // RNE
    return (unsigned short)u;
}

// ---- device-wide barrier (per-XCD L2s are non-coherent: release via
// __threadfence (wbl2) + device-scope atomic; acquire via atomic load +
// __threadfence (buffer_inv)). All 256 blocks structurally resident:
// 1 block/CU needs only 60KB LDS / <=512 VGPR. ----
__device__ __forceinline__ void gridbar(unsigned int* ctr, int slot) {
    __syncthreads();   // compiler emits s_waitcnt vmcnt(0) before s_barrier -> stores drained
    if (threadIdx.x == 0) {
        __threadfence();
        __hip_atomic_fetch_add(&ctr[slot], 1u, __ATOMIC_ACQ_REL, __HIP_MEMORY_SCOPE_AGENT);
        while (__hip_atomic_load(&ctr[slot], __ATOMIC_ACQUIRE, __HIP_MEMORY_SCOPE_AGENT) < 256u)
            __builtin_amdgcn_s_sleep(2);
        __threadfence();
    }
    __syncthreads();
}

__device__ __forceinline__ void bmv(float s1, float s2, float* red8,
                                    float& mean, float& rstd) {
    int t = threadIdx.x;
    #pragma unroll
    for (int o = 32; o > 0; o >>= 1) { s1 += __shfl_down(s1, o); s2 += __shfl_down(s2, o); }
    __syncthreads();
    if ((t & 63) == 0) { red8[t >> 6] = s1; red8[4 + (t >> 6)] = s2; }
    __syncthreads();
    float a1 = red8[0] + red8[1] + red8[2] + red8[3];
    float a2 = red8[4] + red8[5] + red8[6] + red8[7];
    mean = a1 * (1.0f / HD);
    rstd = rsqrtf(a2 * (1.0f / HD) - mean * mean + 1e-5f);
}

// ---------------------------------------------------------------------------
// 80-row GEMM tile: Y[80][NT] += Xeff[80][64*nchunks] @ W[NT][...]^T
// All 80 rows staged per block -> each W byte staged exactly once per block.
// Thread tile 10 rows x NT/32 cols. Wt[k][NT+1] (stores 2-way free, reads
// conflict-free); Xs[row][68] (2-way on reads = free).
// xmode: 0 plain, 1 fq row%5, 2 gelu(sum of 8 partials + bias).
// ---------------------------------------------------------------------------
template <int NT>
__device__ void gemm80(const float* __restrict__ Xb, int ldx, int xmode,
                       const float* __restrict__ gbias, int gstr,
                       const float* __restrict__ Wb, int ldw,
                       float* __restrict__ Yb, int ldy,
                       int nchunks, float* lds)
{
    float* Wt = lds;
    float* Xs = lds + 64 * (NT + 1);
    const int ldwt = NT + 1;
    int t = threadIdx.x;
    int c = t & 31, rg = t >> 5;
    float acc[10][NT / 32];
    #pragma unroll
    for (int r = 0; r < 10; ++r)
        #pragma unroll
        for (int j = 0; j < NT / 32; ++j) acc[r][j] = 0.f;

    for (int ch = 0; ch < nchunks; ++ch) {
        int kc = ch * 64;
        __syncthreads();
        for (int idx = t; idx < 1280; idx += 256) {
            int row = idx >> 4, qq = idx & 15;
            const float* p0 = Xb + (size_t)(xmode == 1 ? (row % FH) : row) * ldx + kc + qq * 4;
            float4 xv;
            if (xmode == 2) {
                float4 s0 = *(const float4*)p0;
                #pragma unroll
                for (int z = 1; z < 8; ++z) {
                    float4 pz = *(const float4*)(p0 + (size_t)z * gstr);
                    s0.x += pz.x; s0.y += pz.y; s0.z += pz.z; s0.w += pz.w;
                }
                float4 bi = *(const float4*)(gbias + kc + qq * 4);
                xv.x = gelu_f(s0.x + bi.x); xv.y = gelu_f(s0.y + bi.y);
                xv.z = gelu_f(s0.z + bi.z); xv.w = gelu_f(s0.w + bi.w);
            } else {
                xv = *(const float4*)p0;
            }
            *(float4*)(Xs + row * 68 + qq * 4) = xv;
        }
        for (int idx = t; idx < NT * 16; idx += 256) {
            int cc = idx >> 4, qq = idx & 15;
            float4 wv = *(const float4*)(Wb + (size_t)cc * ldw + kc + qq * 4);
            Wt[(qq * 4 + 0) * ldwt + cc] = wv.x;
            Wt[(qq * 4 + 1) * ldwt + cc] = wv.y;
            Wt[(qq * 4 + 2) * ldwt + cc] = wv.z;
            Wt[(qq * 4 + 3) * ldwt + cc] = wv.w;
        }
        __syncthreads();
        #pragma unroll 2
        for (int k4 = 0; k4 < 16; ++k4) {
            float4 xr[10];
            #pragma unroll
            for (int r = 0; r < 10; ++r)
                xr[r] = *(const float4*)(Xs + (rg * 10 + r) * 68 + k4 * 4);
            #pragma unroll
            for (int i = 0; i < 4; ++i) {
                int k = k4 * 4 + i;
                float w[NT / 32];
                #pragma unroll
                for (int j = 0; j < NT / 32; ++j) w[j] = Wt[k * ldwt + c + 32 * j];
                #pragma unroll
                for (int r = 0; r < 10; ++r) {
                    float xv = ((const float*)&xr[r])[i];
                    #pragma unroll
                    for (int j = 0; j < NT / 32; ++j)
                        acc[r][j] = fmaf(xv, w[j], acc[r][j]);
                }
            }
        }
    }
    #pragma unroll
    for (int r = 0; r < 10; ++r) {
        float* yr = Yb + (size_t)(rg * 10 + r) * ldy + c;
        #pragma unroll
        for (int j = 0; j < NT / 32; ++j) yr[32 * j] = acc[r][j];
    }
}

// ---------------------------------------------------------------------------
__device__ void attn_sa_phase(int l, const float* __restrict__ qkvp,
                              const float* __restrict__ in_b,
                              float* __restrict__ ao, float* lds)
{
    int blk = blockIdx.x;
    int b = blk >> 3, h = blk & 7, t = threadIdx.x;
    float* qkv = lds;          // [3][5][64]
    float* sc  = lds + 960;
    float* aw  = lds + 1024;
    for (int idx = t; idx < 960; idx += 256) {
        int m = idx / 320, rem = idx - m * 320;
        int tok = rem >> 6, d = rem & 63;
        int col = m * HD + h * 64 + d;
        size_t o = (size_t)(b * FH + tok) * 1536 + col;
        float v = in_b[l * 1536 + col];
        #pragma unroll
        for (int z = 0; z < 8; ++z) v += qkvp[(size_t)z * 122880 + o];
        qkv[(m * FH + tok) * 64 + d] = v;
    }
    __syncthreads();
    if (t < 25) {
        int tq = t / 5, tu = t % 5;
        float s = 0;
        for (int d = 0; d < 64; ++d) s += qkv[tq * 64 + d] * qkv[(FH + tu) * 64 + d];
        sc[tq * 5 + tu] = s * 0.125f;
    }
    __syncthreads();
    if (t < 5) {
        float mx = -1e30f;
        for (int u = 0; u < 5; ++u) mx = fmaxf(mx, sc[t * 5 + u]);
        float e[5], sm = 0;
        for (int u = 0; u < 5; ++u) { e[u] = expf(sc[t * 5 + u] - mx); sm += e[u]; }
        for (int u = 0; u < 5; ++u) aw[t * 5 + u] = e[u] / sm;
    }
    __syncthreads();
    if (t < 64) {
        for (int tok = 0; tok < FH; ++tok) {
            float o = 0;
            for (int u = 0; u < 5; ++u) o += aw[tok * 5 + u] * qkv[(2 * FH + u) * 64 + t];
            ao[(size_t)(b * FH + tok) * HD + h * 64 + t] = o;
        }
    }
}

__device__ void attn_ca_phase(int l, const float* __restrict__ qp,
                              const float* __restrict__ kvb,
                              const float* __restrict__ ca_in_b,
                              float* __restrict__ ao, float* lds)
{
    int blk = blockIdx.x;
    int b = blk >> 3, h = blk & 7, t = threadIdx.x;
    float* q  = lds;           // 5*64
    float* kl = lds + 320;     // 10*64
    float* vl = lds + 960;     // 10*64
    float* sc = lds + 1600;    // 50
    float* aw = lds + 1664;    // 50
    const float* bb = ca_in_b + l * 1536;
    for (int idx = t; idx < 320; idx += 256) {
        int tok = idx >> 6, d = idx & 63;
        size_t o = (size_t)(b * FH + tok) * HD + h * 64 + d;
        float v = bb[h * 64 + d];
        #pragma unroll
        for (int z = 0; z < 8; ++z) v += qp[(size_t)z * 40960 + o];
        q[tok * 64 + d] = v;
    }
    for (int idx = t; idx < 640; idx += 256) {
        int u = idx >> 6, d = idx & 63;
        size_t o  = (size_t)(l * 160 + b * TM + u) * 1024 + h * 64 + d;
        size_t o2 = o + (size_t)2 * 160 * 1024;   // zk=1 partial
        kl[u * 64 + d] = kvb[o] + kvb[o2] + bb[HD + h * 64 + d];
        vl[u * 64 + d] = kvb[o + 512] + kvb[o2 + 512] + bb[2 * HD + h * 64 + d];
    }
    __syncthreads();
    if (t < 50) {
        int tq = t / TM, tu = t % TM;
        float s = 0;
        for (int d = 0; d < 64; ++d) s += q[tq * 64 + d] * kl[tu * 64 + d];
        sc[tq * TM + tu] = s * 0.125f;
    }
    __syncthreads();
    if (t < 5) {
        float mx = -1e30f;
        for (int u = 0; u < TM; ++u) mx = fmaxf(mx, sc[t * TM + u]);
        float e[TM], sm = 0;
        for (int u = 0; u < TM; ++u) { e[u] = expf(sc[t * TM + u] - mx); sm += e[u]; }
        for (int u = 0; u < TM; ++u) aw[t * TM + u] = e[u] / sm;
    }
    __syncthreads();
    if (t < 64) {
        for (int tok = 0; tok < FH; ++tok) {
            float o = 0;
            for (int u = 0; u < TM; ++u) o += aw[tok * TM + u] * vl[u * 64 + t];
            ao[(size_t)(b * FH + tok) * HD + h * 64 + t] = o;
        }
    }
}

// residual + sum(8 partials) + bias + LN (optional second LN), 5 rows/block.
__device__ void ln5(const float* __restrict__ res, int fqmode,
                    const float* __restrict__ bias,
                    const float* __restrict__ parts, int pstr,
                    const float* __restrict__ lw, const float* __restrict__ lb,
                    float* __restrict__ xo,
                    const float* __restrict__ fw, const float* __restrict__ fb,
                    float* __restrict__ xn, float* lds)
{
    int blk = blockIdx.x, t = threadIdx.x;
    for (int rr = 0; rr < 5; ++rr) {
        int r = blk * 5 + rr;
        int c0 = t * 2;
        int rres = fqmode ? (r % FH) : r;
        float v0 = res[(size_t)rres * HD + c0] + bias[c0];
        float v1 = res[(size_t)rres * HD + c0 + 1] + bias[c0 + 1];
        #pragma unroll
        for (int z = 0; z < 8; ++z) {
            v0 += parts[(size_t)z * pstr + (size_t)r * HD + c0];
            v1 += parts[(size_t)z * pstr + (size_t)r * HD + c0 + 1];
        }
        float mean, rstd;
        bmv(v0 + v1, v0 * v0 + v1 * v1, lds, mean, rstd);
        float o0 = (v0 - mean) * rstd * lw[c0] + lb[c0];
        float o1 = (v1 - mean) * rstd * lw[c0 + 1] + lb[c0 + 1];
        xo[(size_t)r * HD + c0] = o0;
        xo[(size_t)r * HD + c0 + 1] = o1;
        if (xn) {
            float m2, rs2;
            bmv(o0 + o1, o0 * o0 + o1 * o1, lds, m2, rs2);
            xn[(size_t)r * HD + c0] = (o0 - m2) * rs2 * fw[c0] + fb[c0];
            xn[(size_t)r * HD + c0 + 1] = (o1 - m2) * rs2 * fw[c0 + 1] + fb[c0 + 1];
        }
    }
}

// M = pe2^T @ [pred;ex]^T folded, stored as bf16 MFMA B-frags; cb = combined bias.
__device__ void mprep(int m, const float* __restrict__ pe2_w, const float* __restrict__ pe2_b,
                      const float* __restrict__ pred_w, const float* __restrict__ pred_b,
                      const float* __restrict__ ex_w, const float* __restrict__ ex_b,
                      unsigned short* __restrict__ Mbf, float* __restrict__ cb, float* lds)
{
    int t = threadIdx.x;
    if (m < 16) {
        int dl = t & 31, ec = t >> 5;
        int d = m * 32 + dl;
        float acc[27];
        #pragma unroll
        for (int k = 0; k < 27; ++k) acc[k] = 0.f;
        for (int e = ec * 64; e < ec * 64 + 64; ++e) {
            float wv = pe2_w[(size_t)e * HD + d];
            #pragma unroll
            for (int k = 0; k < 26; ++k) acc[k] = fmaf(wv, pred_w[k * HD + e], acc[k]);
            acc[26] = fmaf(wv, ex_w[e], acc[26]);
        }
        #pragma unroll
        for (int k = 0; k < 27; ++k) lds[(ec * 32 + dl) * 27 + k] = acc[k];
        __syncthreads();
        for (int idx = t; idx < 1024; idx += 256) {
            int dl2 = idx >> 5, k = idx & 31;
            float s = 0.f;
            if (k < 27) {
                #pragma unroll
                for (int e = 0; e < 8; ++e) s += lds[(e * 32 + dl2) * 27 + k];
            }
            int quad = dl2 >> 3, j = dl2 & 7;
            int nt = k >> 4, n15 = k & 15;
            int lane = quad * 16 + n15;
            // B-frag layout: lane holds B[k=quad*8+j][n=lane&15] (kstep = m)
            Mbf[((size_t)(m * 2 + nt) * 64 + lane) * 8 + j] = f2bf(s);
        }
    } else {
        int g = t >> 3, li = t & 7;
        if (g < 27) {
            const float* wo = (g < 26) ? (pred_w + g * HD) : ex_w;
            float a = 0.f;
            for (int e = li; e < HD; e += 8) a += pe2_b[e] * wo[e];
            a += __shfl_down(a, 4, 8);
            a += __shfl_down(a, 2, 8);
            a += __shfl_down(a, 1, 8);
            if (li == 0) cb[g] = a + ((g < 26) ? pred_b[g] : ex_b[0]);
        }
    }
}

// Pair head via MFMA: block = (b, f, third of 128 pairs); stage S(8)/O(20)/C(1)
// rows in LDS; G = gelu(S+O+C) -> bf16 A-frags; B-frags streamed from Mbf.
__device__ void pair_phase(const float* __restrict__ SOp, const float* __restrict__ cpb,
                           const float* __restrict__ pe1_b,
                           const unsigned short* __restrict__ Mbf,
                           const float* __restrict__ cb,
                           float* __restrict__ out, float* lds)
{
    int blk = blockIdx.x;
    int third = blk % 3, bf = blk / 3;
    int b = bf / FH, f = bf % FH;
    int t = threadIdx.x;
    int wv = t >> 6, lane = t & 63;
    int quad = lane >> 4, n15 = lane & 15;
    int i0 = (third == 0) ? 0 : (third == 1 ? 6 : 13);

    for (int idx = t; idx < 29 * 128; idx += 256) {
        int row = idx >> 7, c4 = (idx & 127) << 2;
        float4 v;
        if (row < 8) {
            int i = i0 + row; if (i > 19) i = 19;
            size_t o = (size_t)(b * NO + i) * 1024 + c4;
            v = *(const float4*)(SOp + o);
            #pragma unroll
            for (int z = 1; z < 4; ++z) {
                float4 p = *(const float4*)(SOp + (size_t)z * 327680 + o);
                v.x += p.x; v.y += p.y; v.z += p.z; v.w += p.w;
            }
        } else if (row < 28) {
            int j = row - 8;
            size_t o = (size_t)(b * NO + j) * 1024 + 512 + c4;
            v = *(const float4*)(SOp + o);
            #pragma unroll
            for (int z = 1; z < 4; ++z) {
                float4 p = *(const float4*)(SOp + (size_t)z * 327680 + o);
                v.x += p.x; v.y += p.y; v.z += p.z; v.w += p.w;
            }
        } else {
            size_t o = (size_t)(b * FH + f) * HD + c4;
            float4 s = *(const float4*)(cpb + o);
            #pragma unroll
            for (int z = 1; z < 8; ++z) {
                float4 p = *(const float4*)(cpb + (size_t)z * 40960 + o);
                s.x += p.x; s.y += p.y; s.z += p.z; s.w += p.w;
            }
            float4 pb = *(const float4*)(pe1_b + c4);
            v.x = s.x + pb.x; v.y = s.y + pb.y; v.z = s.z + pb.z; v.w = s.w + pb.w;
        }
        *(float4*)(lds + row * 516 + c4) = v;
    }
    __syncthreads();

    floatx4 acc00 = {0,0,0,0}, acc01 = {0,0,0,0}, acc10 = {0,0,0,0}, acc11 = {0,0,0,0};
    for (int ks = 0; ks < 16; ++ks) {
        bf16x8 b0 = *(const bf16x8*)(Mbf + ((size_t)(ks * 2 + 0) * 64 + lane) * 8);
        bf16x8 b1 = *(const bf16x8*)(Mbf + ((size_t)(ks * 2 + 1) * 64 + lane) * 8);
        #pragma unroll
        for (int mt = 0; mt < 2; ++mt) {
            int p = third * 128 + wv * 32 + mt * 16 + n15;   // A row m = lane&15
            bf16x8 afr = {0, 0, 0, 0, 0, 0, 0, 0};
            if (p < NP) {
                int i = p / 19, j0 = p % 19;
                int j = j0 + (j0 >= i ? 1 : 0);
                int dof = ks * 32 + quad * 8;                // A k = quad*8+j
                const float* Sr = lds + (i - i0) * 516 + dof;
                const float* Or = lds + (8 + j) * 516 + dof;
                const float* Cr = lds + 28 * 516 + dof;
                float4 sa = *(const float4*)Sr, sb = *(const float4*)(Sr + 4);
                float4 oa = *(const float4*)Or, ob = *(const float4*)(Or + 4);
                float4 ca = *(const float4*)Cr, cc = *(const float4*)(Cr + 4);
                union { unsigned short u[8]; bf16x8 v8; } pk;
                pk.u[0] = f2bf(gelu_f(sa.x + oa.x + ca.x));
                pk.u[1] = f2bf(gelu_f(sa.y + oa.y + ca.y));
                pk.u[2] = f2bf(gelu_f(sa.z + oa.z + ca.z));
                pk.u[3] = f2bf(gelu_f(sa.w + oa.w + ca.w));
                pk.u[4] = f2bf(gelu_f(sb.x + ob.x + cc.x));
                pk.u[5] = f2bf(gelu_f(sb.y + ob.y + cc.y));
                pk.u[6] = f2bf(gelu_f(sb.z + ob.z + cc.z));
                pk.u[7] = f2bf(gelu_f(sb.w + ob.w + cc.w));
                afr = pk.v8;
            }
            if (mt == 0) {
                acc00 = __builtin_amdgcn_mfma_f32_16x16x32_bf16(afr, b0, acc00, 0, 0, 0);
                acc01 = __builtin_amdgcn_mfma_f32_16x16x32_bf16(afr, b1, acc01, 0, 0, 0);
            } else {
                acc10 = __builtin_amdgcn_mfma_f32_16x16x32_bf16(afr, b0, acc10, 0, 0, 0);
                acc11 = __builtin_amdgcn_mfma_f32_16x16x32_bf16(afr, b1, acc11, 0, 0, 0);
            }
        }
    }
    int pbase = (b * FH + f) * NP;
    #pragma unroll
    for (int mt = 0; mt < 2; ++mt) {
        #pragma unroll
        for (int nt = 0; nt < 2; ++nt) {
            floatx4 a = (mt == 0) ? (nt == 0 ? acc00 : acc01)
                                  : (nt == 0 ? acc10 : acc11);
            int n = nt * 16 + n15;                 // D col = lane&15
            #pragma unroll
            for (int reg = 0; reg < 4; ++reg) {
                int p = third * 128 + wv * 32 + mt * 16 + quad * 4 + reg;  // D row
                if (p < NP && n < 27) {
                    float vout = a[reg] + cb[n];
                    if (n < 26) out[(size_t)(pbase + p) * 26 + n] = vout;
                    else        out[PRED_N + pbase + p] = vout;
                }
            }
        }
    }
}

// ---------------------------------------------------------------------------
__global__ void __launch_bounds__(256)
k_mega(const float* temporal, const float* objf, const float* fq,
       const float* sa_in_w, const float* sa_in_b,
       const float* sa_out_w, const float* sa_out_b,
       const float* ca_in_w, const float* ca_in_b,
       const float* ca_out_w, const float* ca_out_b,
       const float* ff1_w, const float* ff1_b,
       const float* ff2_w, const float* ff2_b,
       const float* n1_w, const float* n1_b,
       const float* n2_w, const float* n2_b,
       const float* n3_w, const float* n3_b,
       const float* norm_w, const float* norm_b,
       const float* pe1_w, const float* pe1_b,
       const float* pe2_w, const float* pe2_b,
       const float* pred_w, const float* pred_b,
       const float* ex_w, const float* ex_b,
       float* ws, float* out)
{
    __shared__ float lds[15040];   // 60.2 KB, unioned across phases
    unsigned int* ctr = (unsigned int*)ws;
    float* x1   = ws + 1024;
    float* x2   = x1 + 40960;
    float* x3   = x2 + 40960;
    float* xn   = x3 + 40960;
    float* ao   = xn + 40960;
    float* qkvp = ao + 40960;        // 8 x 80 x 1536
    float* qp   = qkvp + 983040;     // 8 x 80 x 512
    float* yp   = qp + 327680;       // 8 x 80 x 512
    float* ffp  = yp + 327680;       // 8 x 80 x 2048
    float* kvb  = ffp + 1310720;     // zk2 x l2 x 160 x 1024
    float* SOp  = kvb + 655360;      // zk4 x 320 x 1024
    float* cpb  = SOp + 1310720;     // 8 x 80 x 512
    unsigned short* Mbf = (unsigned short*)(cpb + 327680);  // 16384 ushort
    float* cb   = cpb + 327680 + 8192;
    int blk = blockIdx.x;
    int slot = 0;

    // ---- P0: PREP: CA K/V (128) | SA-QKV l0 (96) | M fold (17) ----
    if (blk < 128) {
        int zk = blk & 1, l = (blk >> 1) & 1, y = (blk >> 2) & 1, x = blk >> 3;
        int nb = x * 64, kb = zk * 256;
        gemm80<64>(temporal + (size_t)(y * 80) * HD + kb, HD, 0, nullptr, 0,
                   ca_in_w + (size_t)(l * 1536 + 512 + nb) * HD + kb, HD,
                   kvb + (size_t)((zk * 2 + l) * 160 + y * 80) * 1024 + nb, 1024, 4, lds);
    } else if (blk < 224) {
        int qi = blk - 128, x = qi % 12, zk = qi / 12;
        int nb = x * 128, kb = zk * 64;
        gemm80<128>(fq + kb, HD, 1, nullptr, 0,
                    sa_in_w + (size_t)nb * HD + kb, HD,
                    qkvp + (size_t)zk * 122880 + nb, 1536, 1, lds);
    } else if (blk < 241) {
        mprep(blk - 224, pe2_w, pe2_b, pred_w, pred_b, ex_w, ex_b, Mbf, cb, lds);
    }
    gridbar(ctr, slot++);

    for (int l = 0; l < 2; ++l) {
        if (l == 1) {
            if (blk >= 128 && blk < 224) {
                int qi = blk - 128, x = qi % 12, zk = qi / 12;
                int nb = x * 128, kb = zk * 64;
                gemm80<128>(x3 + kb, HD, 0, nullptr, 0,
                            sa_in_w + (size_t)(1536 + nb) * HD + kb, HD,
                            qkvp + (size_t)zk * 122880 + nb, 1536, 1, lds);
            }
            gridbar(ctr, slot++);
        }
        // ATTN_SA (+ S/O projections at l0)
        if (blk < 128) {
            attn_sa_phase(l, qkvp, sa_in_b, ao, lds);
        } else if (l == 0) {
            int s = blk - 128;
            int zw = s & 1, x = (s >> 1) & 3, y = (s >> 3) & 3, zk = s >> 5;
            int nb = x * 128, kb = zk * 128;
            gemm80<128>(objf + (size_t)(y * 80) * HD + kb, HD, 0, nullptr, 0,
                        pe1_w + (size_t)nb * 1536 + zw * 512 + kb, 1536,
                        SOp + (size_t)zk * 327680 + (size_t)(y * 80) * 1024 + zw * 512 + nb,
                        1024, 2, lds);
        }
        gridbar(ctr, slot++);
        // SAPROJ
        if (blk < 64) {
            int x = blk & 7, zk = blk >> 3;
            int nb = x * 64, kb = zk * 64;
            gemm80<64>(ao + kb, HD, 0, nullptr, 0,
                       sa_out_w + (size_t)(l * 512 + nb) * HD + kb, HD,
                       yp + (size_t)zk * 40960 + nb, HD, 1, lds);
        }
        gridbar(ctr, slot++);
        // LN1
        if (blk < 16)
            ln5(l == 0 ? fq : x3, l == 0 ? 1 : 0, sa_out_b + l * HD,
                yp, 40960, n1_w + l * HD, n1_b + l * HD, x1,
                nullptr, nullptr, nullptr, lds);
        gridbar(ctr, slot++);
        // CAQ
        if (blk < 64) {
            int x = blk & 7, zk = blk >> 3;
            int nb = x * 64, kb = zk * 64;
            gemm80<64>(x1 + kb, HD, 0, nullptr, 0,
                       ca_in_w + (size_t)(l * 1536 + nb) * HD + kb, HD,
                       qp + (size_t)zk * 40960 + nb, HD, 1, lds);
        }
        gridbar(ctr, slot++);
        // ATTN_CA
        if (blk < 128) attn_ca_phase(l, qp, kvb, ca_in_b, ao, lds);
        gridbar(ctr, slot++);
        // CAPROJ
        if (blk < 64) {
            int x = blk & 7, zk = blk >> 3;
            int nb = x * 64, kb = zk * 64;
            gemm80<64>(ao + kb, HD, 0, nullptr, 0,
                       ca_out_w + (size_t)(l * 512 + nb) * HD + kb, HD,
                       yp + (size_t)zk * 40960 + nb, HD, 1, lds);
        }
        gridbar(ctr, slot++);
        // LN2
        if (blk < 16)
            ln5(x1, 0, ca_out_b + l * HD, yp, 40960,
                n2_w + l * HD, n2_b + l * HD, x2, nullptr, nullptr, nullptr, lds);
        gridbar(ctr, slot++);
        // FF1
        if (blk < 128) {
            int x = blk & 15, zk = blk >> 4;
            int nb = x * 128, kb = zk * 64;
            gemm80<128>(x2 + kb, HD, 0, nullptr, 0,
                        ff1_w + (size_t)l * 1048576 + (size_t)nb * HD + kb, HD,
                        ffp + (size_t)zk * 163840 + nb, FFD, 1, lds);
        }
        gridbar(ctr, slot++);
        // FF2 (gelu of summed FF1 partials in staging)
        if (blk < 64) {
            int x = blk & 7, zk = blk >> 3;
            int nb = x * 64, kb = zk * 256;
            gemm80<64>(ffp + kb, FFD, 2, ff1_b + l * FFD + kb, 163840,
                       ff2_w + (size_t)l * 1048576 + (size_t)nb * FFD + kb, FFD,
                       yp + (size_t)zk * 40960 + nb, HD, 4, lds);
        }
        gridbar(ctr, slot++);
        // LN3 (+ final LN at l1)
        if (blk < 16) {
            if (l == 0)
                ln5(x2, 0, ff2_b, yp, 40960, n3_w, n3_b, x3,
                    nullptr, nullptr, nullptr, lds);
            else
                ln5(x2, 0, ff2_b + HD, yp, 40960, n3_w + HD, n3_b + HD, x3,
                    norm_w, norm_b, xn, lds);
        }
        gridbar(ctr, slot++);
    }
    // NORMC: ctx projection (pe1_w cols [1024,1536))
    if (blk < 64) {
        int x = blk & 7, zk = blk >> 3;
        int nb = x * 64, kb = zk * 64;
        gemm80<64>(xn + kb, HD, 0, nullptr, 0,
                   pe1_w + (size_t)nb * 1536 + 1024 + kb, 1536,
                   cpb + (size_t)zk * 40960 + nb, HD, 1, lds);
    }
    gridbar(ctr, slot++);
    // PAIR
    if (blk < 240)
        pair_phase(SOp, cpb, pe1_b, Mbf, cb, out, lds);
}

// ---------------------------------------------------------------------------
extern "C" void kernel_launch(void* const* d_in, const int* in_sizes, int n_in,
                              void* d_out, int out_size, void* d_ws, size_t ws_size,
                              hipStream_t stream) {
    const float* temporal = (const float*)d_in[0];
    const float* objf     = (const float*)d_in[1];
    const float* fq       = (const float*)d_in[2];
    const float* sa_in_w  = (const float*)d_in[3];
    const float* sa_in_b  = (const float*)d_in[4];
    const float* sa_out_w = (const float*)d_in[5];
    const float* sa_out_b = (const float*)d_in[6];
    const float* ca_in_w  = (const float*)d_in[7];
    const float* ca_in_b  = (const float*)d_in[8];
    const float* ca_out_w = (const float*)d_in[9];
    const float* ca_out_b = (const float*)d_in[10];
    const float* ff1_w    = (const float*)d_in[11];
    const float* ff1_b    = (const float*)d_in[12];
    const float* ff2_w    = (const float*)d_in[13];
    const float* ff2_b    = (const float*)d_in[14];
    const float* n1_w     = (const float*)d_in[15];
    const float* n1_b     = (const float*)d_in[16];
    const float* n2_w     = (const float*)d_in[17];
    const float* n2_b     = (const float*)d_in[18];
    const float* n3_w     = (const float*)d_in[19];
    const float* n3_b     = (const float*)d_in[20];
    const float* norm_w   = (const float*)d_in[21];
    const float* norm_b   = (const float*)d_in[22];
    const float* pe1_w    = (const float*)d_in[23];
    const float* pe1_b    = (const float*)d_in[24];
    const float* pe2_w    = (const float*)d_in[25];
    const float* pe2_b    = (const float*)d_in[26];
    const float* pred_w   = (const float*)d_in[27];
    const float* pred_b   = (const float*)d_in[28];
    const float* ex_w     = (const float*)d_in[29];
    const float* ex_b     = (const float*)d_in[30];

    // zero the grid-barrier counters (d_ws is re-poisoned 0xAA before each run)
    hipMemsetAsync(d_ws, 0, 4096, stream);
    k_mega<<<256, 256, 0, stream>>>(
        temporal, objf, fq, sa_in_w, sa_in_b, sa_out_w, sa_out_b,
        ca_in_w, ca_in_b, ca_out_w, ca_out_b, ff1_w, ff1_b, ff2_w, ff2_b,
        n1_w, n1_b, n2_w, n2_b, n3_w, n3_b, norm_w, norm_b,
        pe1_w, pe1_b, pe2_w, pe2_b, pred_w, pred_b, ex_w, ex_b,
        (float*)d_ws, (float*)d_out);
}

// Round 6
// 415.503 us; speedup vs baseline: 3.7594x; 3.7594x over previous
//
#include <hip/hip_runtime.h>
#include <math.h>

// H=512, heads=8, dh=64, L=2, FF=2048, B=16, Fh=5, Tmem=10, Nobj=20, P=380.
#define HD 512
#define FFD 2048
#define FH 5
#define TM 10
#define NO 20
#define NP 380
#define PRED_N 790400   // 16*5*380*26

#define XM_PLAIN 0
#define XM_GELU  1
#define XM_FQ    2
#define XM_LN    3
#define XM_LN2   4

typedef short bf16x8 __attribute__((ext_vector_type(8)));
typedef float floatx4 __attribute__((ext_vector_type(4)));

__device__ __forceinline__ float gelu_f(float v) {
    return 0.5f * v * (1.0f + erff(v * 0.70710678118654752440f));
}
__device__ __forceinline__ unsigned short f2bf(float x) {
    unsigned int u = __float_as_uint(x);
    u = (u + 0x7FFFu + ((u >> 16) & 1u)) >> 16;   // RNE
    return (unsigned short)u;
}

// ---------------------------------------------------------------------------
// R4-proven tiled GEMM body with fused prologues, as a device function.
// Block tile RT x 128 (RT=16 normal, RT=8 for LN modes), K-chunk 64.
// Wt transposed stride 129 (stores 2-way free, reads conflict-free).
// lds must be >= 12352 floats (Wt 8256 + Xs 4096).
// ---------------------------------------------------------------------------
__device__ __forceinline__ void gemm_body(
    int bx, int by, int bz,
    const float* __restrict__ X, int ldx, int xmode,
    const float* __restrict__ parts, int np, int pzstr,
    const float* __restrict__ bo,
    const float* __restrict__ lw, const float* __restrict__ lb,
    const float* __restrict__ fw, const float* __restrict__ fb,
    float* __restrict__ xout, int xmod, int gps,
    const float* __restrict__ W, int ldw,
    float* __restrict__ Y, int ldy, int zyoff,
    int Klen, float* lds)
{
    float* Wt = lds;            // 64*129
    float* Xs = lds + 8256;     // 4096
    int t = threadIdx.x;
    int nb = bx * 128;
    int z  = bz;
    int rt = (xmode >= XM_LN) ? 8 : 16;
    int r0 = by * rt;
    int kbase = z * Klen;
    float* Yb = Y + (size_t)z * zyoff;
    int c  = t & 31;
    int rg = t >> 5;
    int sc = t >> 4;
    int q  = t & 15;

    if (xmode >= XM_LN) {
        int rl = t >> 5;
        int r  = r0 + rl;
        int c0 = (t & 31) * 16;
        int rr = xmod ? (r % xmod) : r;
        float v[16];
        #pragma unroll
        for (int u = 0; u < 16; u += 4) {
            float4 a = *(const float4*)(X + (size_t)rr * ldx + c0 + u);
            float4 bb = *(const float4*)(bo + c0 + u);
            float vx = a.x + bb.x, vy = a.y + bb.y, vz = a.z + bb.z, vw = a.w + bb.w;
            for (int zz = 0; zz < np; ++zz) {
                float4 p = *(const float4*)(parts + (size_t)zz * pzstr + (size_t)r * HD + c0 + u);
                vx += p.x; vy += p.y; vz += p.z; vw += p.w;
            }
            v[u] = vx; v[u + 1] = vy; v[u + 2] = vz; v[u + 3] = vw;
        }
        float s1 = 0, s2 = 0;
        #pragma unroll
        for (int u = 0; u < 16; ++u) { s1 += v[u]; s2 += v[u] * v[u]; }
        #pragma unroll
        for (int o = 16; o > 0; o >>= 1) {
            s1 += __shfl_down(s1, o, 32);
            s2 += __shfl_down(s2, o, 32);
        }
        s1 = __shfl(s1, 0, 32); s2 = __shfl(s2, 0, 32);
        float mean = s1 * (1.0f / HD);
        float rstd = rsqrtf(s2 * (1.0f / HD) - mean * mean + 1e-5f);
        #pragma unroll
        for (int u = 0; u < 16; ++u)
            v[u] = (v[u] - mean) * rstd * lw[c0 + u] + lb[c0 + u];
        if (xout && z == 0 && bx == 0) {
            #pragma unroll
            for (int u = 0; u < 16; u += 4)
                *(float4*)(xout + (size_t)r * HD + c0 + u) =
                    make_float4(v[u], v[u + 1], v[u + 2], v[u + 3]);
        }
        if (xmode == XM_LN2) {
            float t1 = 0, t2 = 0;
            #pragma unroll
            for (int u = 0; u < 16; ++u) { t1 += v[u]; t2 += v[u] * v[u]; }
            #pragma unroll
            for (int o = 16; o > 0; o >>= 1) {
                t1 += __shfl_down(t1, o, 32);
                t2 += __shfl_down(t2, o, 32);
            }
            t1 = __shfl(t1, 0, 32); t2 = __shfl(t2, 0, 32);
            float m2 = t1 * (1.0f / HD);
            float rs2 = rsqrtf(t2 * (1.0f / HD) - m2 * m2 + 1e-5f);
            #pragma unroll
            for (int u = 0; u < 16; ++u)
                v[u] = (v[u] - m2) * rs2 * fw[c0 + u] + fb[c0 + u];
        }
        #pragma unroll
        for (int u = 0; u < 16; u += 4)
            *(float4*)(Xs + rl * HD + c0 + u) =
                make_float4(v[u], v[u + 1], v[u + 2], v[u + 3]);
        __syncthreads();
    }

    float a00 = 0, a01 = 0, a02 = 0, a03 = 0;
    float a10 = 0, a11 = 0, a12 = 0, a13 = 0;

    for (int kc = 0; kc < Klen; kc += 64) {
        int kg = kbase + kc;
        if (xmode <= XM_FQ) {
            float4 xv;
            if (xmode == XM_PLAIN) {
                xv = *(const float4*)(X + (size_t)(r0 + sc) * ldx + kg + q * 4);
            } else if (xmode == XM_FQ) {
                xv = *(const float4*)(X + (size_t)((r0 + sc) % FH) * ldx + kg + q * 4);
            } else {
                const float* p0 = X + (size_t)(r0 + sc) * ldx + kg + q * 4;
                float4 a = *(const float4*)p0;
                float4 b = *(const float4*)(p0 + gps);
                float4 bi = *(const float4*)(bo + kg + q * 4);
                xv.x = gelu_f(a.x + b.x + bi.x);
                xv.y = gelu_f(a.y + b.y + bi.y);
                xv.z = gelu_f(a.z + b.z + bi.z);
                xv.w = gelu_f(a.w + b.w + bi.w);
            }
            *(float4*)&Xs[sc * 64 + q * 4] = xv;
        }
        #pragma unroll
        for (int p = 0; p < 8; ++p) {
            int cc = sc + p * 16;
            float4 wv = *(const float4*)(W + (size_t)(nb + cc) * ldw + kg + q * 4);
            Wt[(q * 4 + 0) * 129 + cc] = wv.x;
            Wt[(q * 4 + 1) * 129 + cc] = wv.y;
            Wt[(q * 4 + 2) * 129 + cc] = wv.z;
            Wt[(q * 4 + 3) * 129 + cc] = wv.w;
        }
        __syncthreads();
        if (rt == 16) {
            const float* xr0 = &Xs[(rg * 2 + 0) * 64];
            const float* xr1 = &Xs[(rg * 2 + 1) * 64];
            #pragma unroll
            for (int k4 = 0; k4 < 16; ++k4) {
                float4 x0 = *(const float4*)(xr0 + k4 * 4);
                float4 x1 = *(const float4*)(xr1 + k4 * 4);
                const float* x0p = (const float*)&x0;
                const float* x1p = (const float*)&x1;
                #pragma unroll
                for (int i = 0; i < 4; ++i) {
                    const float* wrow = &Wt[(k4 * 4 + i) * 129 + c];
                    float w0 = wrow[0], w1 = wrow[32], w2 = wrow[64], w3 = wrow[96];
                    float xi0 = x0p[i], xi1 = x1p[i];
                    a00 = fmaf(xi0, w0, a00); a01 = fmaf(xi0, w1, a01);
                    a02 = fmaf(xi0, w2, a02); a03 = fmaf(xi0, w3, a03);
                    a10 = fmaf(xi1, w0, a10); a11 = fmaf(xi1, w1, a11);
                    a12 = fmaf(xi1, w2, a12); a13 = fmaf(xi1, w3, a13);
                }
            }
        } else {
            const float* xr0 = &Xs[rg * HD + kg];
            #pragma unroll
            for (int k4 = 0; k4 < 16; ++k4) {
                float4 x0 = *(const float4*)(xr0 + k4 * 4);
                const float* x0p = (const float*)&x0;
                #pragma unroll
                for (int i = 0; i < 4; ++i) {
                    const float* wrow = &Wt[(k4 * 4 + i) * 129 + c];
                    float xi0 = x0p[i];
                    a00 = fmaf(xi0, wrow[0],  a00);
                    a01 = fmaf(xi0, wrow[32], a01);
                    a02 = fmaf(xi0, wrow[64], a02);
                    a03 = fmaf(xi0, wrow[96], a03);
                }
            }
        }
        __syncthreads();
    }
    if (rt == 16) {
        float* yr = Yb + (size_t)(r0 + rg * 2) * ldy + nb + c;
        yr[0] = a00; yr[32] = a01; yr[64] = a02; yr[96] = a03;
        yr += ldy;
        yr[0] = a10; yr[32] = a11; yr[64] = a12; yr[96] = a13;
    } else {
        float* yr = Yb + (size_t)(r0 + rg) * ldy + nb + c;
        yr[0] = a00; yr[32] = a01; yr[64] = a02; yr[96] = a03;
    }
}

__global__ __launch_bounds__(256) void k_gemm(
    const float* __restrict__ X, int ldx, int xmode,
    const float* __restrict__ parts, int np, int pzstr,
    const float* __restrict__ bo,
    const float* __restrict__ lw, const float* __restrict__ lb,
    const float* __restrict__ fw, const float* __restrict__ fb,
    float* __restrict__ xout, int xmod, int gps,
    const float* __restrict__ W, int ldw,
    float* __restrict__ Y, int ldy, int zyoff, int Klen)
{
    __shared__ float lds[12352];
    gemm_body(blockIdx.x, blockIdx.y, blockIdx.z, X, ldx, xmode, parts, np, pzstr,
              bo, lw, lb, fw, fb, xout, xmod, gps, W, ldw, Y, ldy, zyoff, Klen, lds);
}

// ---------------------------------------------------------------------------
// M = pe2^T @ [pred;ex]^T stored as bf16 MFMA B-frags (R5-verified) + cb.
// ---------------------------------------------------------------------------
__device__ void mprep(int m, const float* __restrict__ pe2_w, const float* __restrict__ pe2_b,
                      const float* __restrict__ pred_w, const float* __restrict__ pred_b,
                      const float* __restrict__ ex_w, const float* __restrict__ ex_b,
                      unsigned short* __restrict__ Mbf, float* __restrict__ cb, float* lds)
{
    int t = threadIdx.x;
    if (m < 16) {
        int dl = t & 31, ec = t >> 5;
        int d = m * 32 + dl;
        float acc[27];
        #pragma unroll
        for (int k = 0; k < 27; ++k) acc[k] = 0.f;
        for (int e = ec * 64; e < ec * 64 + 64; ++e) {
            float wv = pe2_w[(size_t)e * HD + d];
            #pragma unroll
            for (int k = 0; k < 26; ++k) acc[k] = fmaf(wv, pred_w[k * HD + e], acc[k]);
            acc[26] = fmaf(wv, ex_w[e], acc[26]);
        }
        #pragma unroll
        for (int k = 0; k < 27; ++k) lds[(ec * 32 + dl) * 27 + k] = acc[k];
        __syncthreads();
        for (int idx = t; idx < 1024; idx += 256) {
            int dl2 = idx >> 5, k = idx & 31;
            float s = 0.f;
            if (k < 27) {
                #pragma unroll
                for (int e = 0; e < 8; ++e) s += lds[(e * 32 + dl2) * 27 + k];
            }
            int quad = dl2 >> 3, j = dl2 & 7;
            int nt = k >> 4, n15 = k & 15;
            int lane = quad * 16 + n15;
            Mbf[((size_t)(m * 2 + nt) * 64 + lane) * 8 + j] = f2bf(s);
        }
    } else {
        int g = t >> 3, li = t & 7;
        if (g < 27) {
            const float* wo = (g < 26) ? (pred_w + g * HD) : ex_w;
            float a = 0.f;
            for (int e = li; e < HD; e += 8) a += pe2_b[e] * wo[e];
            a += __shfl_down(a, 4, 8);
            a += __shfl_down(a, 2, 8);
            a += __shfl_down(a, 1, 8);
            if (li == 0) cb[g] = a + ((g < 26) ? pred_b[g] : ex_b[0]);
        }
    }
}

// ---------------------------------------------------------------------------
// Merged prep: SO gemm [0,320) | CA-KV gemm [320,640) | M fold [640,657).
// ---------------------------------------------------------------------------
__global__ __launch_bounds__(256) void k_prep(
    const float* __restrict__ objf, const float* __restrict__ temporal,
    const float* __restrict__ pe1_w, const float* __restrict__ ca_in_w,
    const float* __restrict__ pe2_w, const float* __restrict__ pe2_b,
    const float* __restrict__ pred_w, const float* __restrict__ pred_b,
    const float* __restrict__ ex_w, const float* __restrict__ ex_b,
    float* __restrict__ SOp, float* __restrict__ kvb,
    unsigned short* __restrict__ Mbf, float* __restrict__ cb)
{
    __shared__ float lds[12352];
    int blk = blockIdx.x;
    if (blk < 320) {
        int zw = blk & 1, zk = (blk >> 1) & 1, ct = (blk >> 2) & 3, y = blk >> 4;
        gemm_body(ct, y, zk, objf, HD, XM_PLAIN, nullptr, 0, 0,
                  nullptr, nullptr, nullptr, nullptr, nullptr, nullptr, 0, 0,
                  pe1_w + zw * 512, 1536,
                  SOp + zw * 512, 1024, 327680, 256, lds);
    } else if (blk < 640) {
        int s = blk - 320;
        int ct = s & 7, l = (s >> 3) & 1, zk = (s >> 4) & 1, y = s >> 5;
        gemm_body(ct, y, zk, temporal, HD, XM_PLAIN, nullptr, 0, 0,
                  nullptr, nullptr, nullptr, nullptr, nullptr, nullptr, 0, 0,
                  ca_in_w + (size_t)(l * 1536 + 512) * HD, HD,
                  kvb + (size_t)((zk * 2 + l) * 160) * 1024, 1024, 0, 256, lds);
    } else {
        mprep(blk - 640, pe2_w, pe2_b, pred_w, pred_b, ex_w, ex_b, Mbf, cb, lds);
    }
}

// ---------------------------------------------------------------------------
// Fused self-attention + out-proj. Block (b, ct, zk): 16*4*4 = 256.
// Phase A: QKV (4 partials + bias) -> LDS, 8-head attn -> ao[5][512].
// Phase B: yp[zk] = ao @ Wout[nb:nb+128, zk*128:+128]^T.
// ---------------------------------------------------------------------------
__global__ __launch_bounds__(256) void k_attnsa_proj(
    int l, const float* __restrict__ qkvp, const float* __restrict__ in_b,
    const float* __restrict__ Wout, float* __restrict__ yp)
{
    __shared__ float lds[11008];
    int bi = blockIdx.x;
    int b = bi >> 4, ct = (bi >> 2) & 3, zk = bi & 3;
    int t = threadIdx.x;
    float* qkv = lds;          // [3*5][512]
    float* sc  = lds + 7680;   // 200
    float* aw  = lds + 7880;   // 200
    float* ao  = lds + 8448;   // [5][512]
    float* Wt  = lds;          // phase B (overlaps dead qkv/sc/aw)

    for (int idx = t; idx < 1920; idx += 256) {
        int tok = idx / 384, c4 = (idx % 384) * 4;
        size_t o = (size_t)(b * FH + tok) * 1536 + c4;
        float4 v = *(const float4*)(in_b + l * 1536 + c4);
        #pragma unroll
        for (int z = 0; z < 4; ++z) {
            float4 p = *(const float4*)(qkvp + (size_t)z * 122880 + o);
            v.x += p.x; v.y += p.y; v.z += p.z; v.w += p.w;
        }
        int m = c4 >> 9, d = c4 & 511;
        *(float4*)(qkv + (size_t)(m * FH + tok) * 512 + d) = v;
    }
    __syncthreads();
    if (t < 200) {
        int h = t / 25, tq = (t / 5) % 5, tu = t % 5;
        float s = 0;
        for (int d = 0; d < 64; ++d)
            s += qkv[tq * 512 + h * 64 + d] * qkv[(FH + tu) * 512 + h * 64 + d];
        sc[t] = s * 0.125f;
    }
    __syncthreads();
    if (t < 40) {
        int base = (t / 5) * 25 + (t % 5) * 5;
        float mx = -1e30f;
        for (int u = 0; u < 5; ++u) mx = fmaxf(mx, sc[base + u]);
        float e[5], sm = 0;
        for (int u = 0; u < 5; ++u) { e[u] = expf(sc[base + u] - mx); sm += e[u]; }
        for (int u = 0; u < 5; ++u) aw[base + u] = e[u] / sm;
    }
    __syncthreads();
    for (int idx = t; idx < 2560; idx += 256) {
        int tok = idx >> 9, c = idx & 511, h = c >> 6;
        float s = 0;
        #pragma unroll
        for (int u = 0; u < 5; ++u)
            s += aw[h * 25 + tok * 5 + u] * qkv[(2 * FH + u) * 512 + c];
        ao[tok * 512 + c] = s;
    }
    int c = t & 31, rg = t >> 5;
    int nb = ct * 128;
    float a0 = 0, a1 = 0, a2 = 0, a3 = 0;
    for (int ch = 0; ch < 2; ++ch) {
        int kg = zk * 128 + ch * 64;
        __syncthreads();
        for (int idx = t; idx < 2048; idx += 256) {
            int cc = idx >> 4, qq = idx & 15;
            float4 wv = *(const float4*)(Wout + (size_t)(nb + cc) * HD + kg + qq * 4);
            Wt[(qq * 4 + 0) * 129 + cc] = wv.x;
            Wt[(qq * 4 + 1) * 129 + cc] = wv.y;
            Wt[(qq * 4 + 2) * 129 + cc] = wv.z;
            Wt[(qq * 4 + 3) * 129 + cc] = wv.w;
        }
        __syncthreads();
        if (rg < FH) {
            const float* xr = ao + rg * 512 + kg;
            #pragma unroll
            for (int k4 = 0; k4 < 16; ++k4) {
                float4 xv = *(const float4*)(xr + k4 * 4);
                #pragma unroll
                for (int i = 0; i < 4; ++i) {
                    const float* wr = &Wt[(k4 * 4 + i) * 129 + c];
                    float x = ((const float*)&xv)[i];
                    a0 = fmaf(x, wr[0],  a0); a1 = fmaf(x, wr[32], a1);
                    a2 = fmaf(x, wr[64], a2); a3 = fmaf(x, wr[96], a3);
                }
            }
        }
    }
    if (rg < FH) {
        float* yr = yp + (size_t)zk * 40960 + (size_t)(b * FH + rg) * HD + nb + c;
        yr[0] = a0; yr[32] = a1; yr[64] = a2; yr[96] = a3;
    }
}

// ---------------------------------------------------------------------------
// Fused cross-attention + out-proj. Block (b, ct, zk): 256 blocks.
// ---------------------------------------------------------------------------
__global__ __launch_bounds__(256) void k_attnca_proj(
    int l, const float* __restrict__ qp, const float* __restrict__ kvb,
    const float* __restrict__ in_b, const float* __restrict__ Wout,
    float* __restrict__ yp)
{
    __shared__ float lds[16160];
    int bi = blockIdx.x;
    int b = bi >> 4, ct = (bi >> 2) & 3, zk = bi & 3;
    int t = threadIdx.x;
    float* q  = lds;            // [5][512]
    float* kl = lds + 2560;     // [10][512]
    float* vl = lds + 7680;     // [10][512]
    float* sc = lds + 12800;    // 400
    float* aw = lds + 13200;    // 400
    float* ao = lds + 13600;    // [5][512]
    float* Wt = lds;            // phase B (overlaps dead q/kl/vl prefix)
    const float* bb = in_b + l * 1536;

    for (int idx = t; idx < 640; idx += 256) {
        int tok = idx / 128, c4 = (idx % 128) * 4;
        size_t o = (size_t)(b * FH + tok) * HD + c4;
        float4 v = *(const float4*)(bb + c4);
        #pragma unroll
        for (int z = 0; z < 4; ++z) {
            float4 p = *(const float4*)(qp + (size_t)z * 40960 + o);
            v.x += p.x; v.y += p.y; v.z += p.z; v.w += p.w;
        }
        *(float4*)(q + tok * 512 + c4) = v;
    }
    for (int idx = t; idx < 1280; idx += 256) {
        int u = idx / 128, c4 = (idx % 128) * 4;
        size_t base = (size_t)(l * 160 + b * TM + u) * 1024;
        float4 k0 = *(const float4*)(kvb + base + c4);
        float4 k1 = *(const float4*)(kvb + 327680 + base + c4);
        float4 bk = *(const float4*)(bb + 512 + c4);
        float4 v0 = *(const float4*)(kvb + base + 512 + c4);
        float4 v1 = *(const float4*)(kvb + 327680 + base + 512 + c4);
        float4 bv = *(const float4*)(bb + 1024 + c4);
        *(float4*)(kl + u * 512 + c4) = make_float4(k0.x + k1.x + bk.x, k0.y + k1.y + bk.y,
                                                    k0.z + k1.z + bk.z, k0.w + k1.w + bk.w);
        *(float4*)(vl + u * 512 + c4) = make_float4(v0.x + v1.x + bv.x, v0.y + v1.y + bv.y,
                                                    v0.z + v1.z + bv.z, v0.w + v1.w + bv.w);
    }
    __syncthreads();
    for (int idx = t; idx < 400; idx += 256) {
        int h = idx / 50, tq = (idx / 10) % 5, tu = idx % 10;
        float s = 0;
        for (int d = 0; d < 64; ++d)
            s += q[tq * 512 + h * 64 + d] * kl[tu * 512 + h * 64 + d];
        sc[idx] = s * 0.125f;
    }
    __syncthreads();
    if (t < 40) {
        int base = (t / 5) * 50 + (t % 5) * 10;
        float mx = -1e30f;
        for (int u = 0; u < TM; ++u) mx = fmaxf(mx, sc[base + u]);
        float e[TM], sm = 0;
        for (int u = 0; u < TM; ++u) { e[u] = expf(sc[base + u] - mx); sm += e[u]; }
        for (int u = 0; u < TM; ++u) aw[base + u] = e[u] / sm;
    }
    __syncthreads();
    for (int idx = t; idx < 2560; idx += 256) {
        int tok = idx >> 9, c = idx & 511, h = c >> 6;
        float s = 0;
        #pragma unroll
        for (int u = 0; u < TM; ++u)
            s += aw[h * 50 + tok * 10 + u] * vl[u * 512 + c];
        ao[tok * 512 + c] = s;
    }
    int c = t & 31, rg = t >> 5;
    int nb = ct * 128;
    float a0 = 0, a1 = 0, a2 = 0, a3 = 0;
    for (int ch = 0; ch < 2; ++ch) {
        int kg = zk * 128 + ch * 64;
        __syncthreads();
        for (int idx = t; idx < 2048; idx += 256) {
            int cc = idx >> 4, qq = idx & 15;
            float4 wv = *(const float4*)(Wout + (size_t)(nb + cc) * HD + kg + qq * 4);
            Wt[(qq * 4 + 0) * 129 + cc] = wv.x;
            Wt[(qq * 4 + 1) * 129 + cc] = wv.y;
            Wt[(qq * 4 + 2) * 129 + cc] = wv.z;
            Wt[(qq * 4 + 3) * 129 + cc] = wv.w;
        }
        __syncthreads();
        if (rg < FH) {
            const float* xr = ao + rg * 512 + kg;
            #pragma unroll
            for (int k4 = 0; k4 < 16; ++k4) {
                float4 xv = *(const float4*)(xr + k4 * 4);
                #pragma unroll
                for (int i = 0; i < 4; ++i) {
                    const float* wr = &Wt[(k4 * 4 + i) * 129 + c];
                    float x = ((const float*)&xv)[i];
                    a0 = fmaf(x, wr[0],  a0); a1 = fmaf(x, wr[32], a1);
                    a2 = fmaf(x, wr[64], a2); a3 = fmaf(x, wr[96], a3);
                }
            }
        }
    }
    if (rg < FH) {
        float* yr = yp + (size_t)zk * 40960 + (size_t)(b * FH + rg) * HD + nb + c;
        yr[0] = a0; yr[32] = a1; yr[64] = a2; yr[96] = a3;
    }
}

// ---------------------------------------------------------------------------
// Pair head via MFMA (R5-verified layouts). grid = 16*5*3 = 240.
// SOp: 2 partials (stride 327680); cpb: 4 partials (stride 40960).
// ---------------------------------------------------------------------------
__global__ __launch_bounds__(256) void k_pair(
    const float* __restrict__ SOp, const float* __restrict__ cpb,
    const float* __restrict__ pe1_b,
    const unsigned short* __restrict__ Mbf, const float* __restrict__ cb,
    float* __restrict__ out)
{
    __shared__ float lds[14964];
    int blk = blockIdx.x;
    int third = blk % 3, bf = blk / 3;
    int b = bf / FH, f = bf % FH;
    int t = threadIdx.x;
    int wv = t >> 6, lane = t & 63;
    int quad = lane >> 4, n15 = lane & 15;
    int i0 = (third == 0) ? 0 : (third == 1 ? 6 : 13);

    for (int idx = t; idx < 29 * 128; idx += 256) {
        int row = idx >> 7, c4 = (idx & 127) << 2;
        float4 v;
        if (row < 8) {
            int i = i0 + row; if (i > 19) i = 19;
            size_t o = (size_t)(b * NO + i) * 1024 + c4;
            float4 p0 = *(const float4*)(SOp + o);
            float4 p1 = *(const float4*)(SOp + 327680 + o);
            v = make_float4(p0.x + p1.x, p0.y + p1.y, p0.z + p1.z, p0.w + p1.w);
        } else if (row < 28) {
            int j = row - 8;
            size_t o = (size_t)(b * NO + j) * 1024 + 512 + c4;
            float4 p0 = *(const float4*)(SOp + o);
            float4 p1 = *(const float4*)(SOp + 327680 + o);
            v = make_float4(p0.x + p1.x, p0.y + p1.y, p0.z + p1.z, p0.w + p1.w);
        } else {
            size_t o = (size_t)(b * FH + f) * HD + c4;
            float4 s = *(const float4*)(cpb + o);
            #pragma unroll
            for (int z = 1; z < 4; ++z) {
                float4 p = *(const float4*)(cpb + (size_t)z * 40960 + o);
                s.x += p.x; s.y += p.y; s.z += p.z; s.w += p.w;
            }
            float4 pb = *(const float4*)(pe1_b + c4);
            v = make_float4(s.x + pb.x, s.y + pb.y, s.z + pb.z, s.w + pb.w);
        }
        *(float4*)(lds + row * 516 + c4) = v;
    }
    __syncthreads();

    floatx4 acc00 = {0,0,0,0}, acc01 = {0,0,0,0}, acc10 = {0,0,0,0}, acc11 = {0,0,0,0};
    for (int ks = 0; ks < 16; ++ks) {
        bf16x8 b0 = *(const bf16x8*)(Mbf + ((size_t)(ks * 2 + 0) * 64 + lane) * 8);
        bf16x8 b1 = *(const bf16x8*)(Mbf + ((size_t)(ks * 2 + 1) * 64 + lane) * 8);
        #pragma unroll
        for (int mt = 0; mt < 2; ++mt) {
            int p = third * 128 + wv * 32 + mt * 16 + n15;
            bf16x8 afr = {0, 0, 0, 0, 0, 0, 0, 0};
            if (p < NP) {
                int i = p / 19, j0 = p % 19;
                int j = j0 + (j0 >= i ? 1 : 0);
                int dof = ks * 32 + quad * 8;
                const float* Sr = lds + (i - i0) * 516 + dof;
                const float* Or = lds + (8 + j) * 516 + dof;
                const float* Cr = lds + 28 * 516 + dof;
                float4 sa = *(const float4*)Sr, sb = *(const float4*)(Sr + 4);
                float4 oa = *(const float4*)Or, ob = *(const float4*)(Or + 4);
                float4 ca = *(const float4*)Cr, cc = *(const float4*)(Cr + 4);
                union { unsigned short u[8]; bf16x8 v8; } pk;
                pk.u[0] = f2bf(gelu_f(sa.x + oa.x + ca.x));
                pk.u[1] = f2bf(gelu_f(sa.y + oa.y + ca.y));
                pk.u[2] = f2bf(gelu_f(sa.z + oa.z + ca.z));
                pk.u[3] = f2bf(gelu_f(sa.w + oa.w + ca.w));
                pk.u[4] = f2bf(gelu_f(sb.x + ob.x + cc.x));
                pk.u[5] = f2bf(gelu_f(sb.y + ob.y + cc.y));
                pk.u[6] = f2bf(gelu_f(sb.z + ob.z + cc.z));
                pk.u[7] = f2bf(gelu_f(sb.w + ob.w + cc.w));
                afr = pk.v8;
            }
            if (mt == 0) {
                acc00 = __builtin_amdgcn_mfma_f32_16x16x32_bf16(afr, b0, acc00, 0, 0, 0);
                acc01 = __builtin_amdgcn_mfma_f32_16x16x32_bf16(afr, b1, acc01, 0, 0, 0);
            } else {
                acc10 = __builtin_amdgcn_mfma_f32_16x16x32_bf16(afr, b0, acc10, 0, 0, 0);
                acc11 = __builtin_amdgcn_mfma_f32_16x16x32_bf16(afr, b1, acc11, 0, 0, 0);
            }
        }
    }
    int pbase = (b * FH + f) * NP;
    #pragma unroll
    for (int mt = 0; mt < 2; ++mt) {
        #pragma unroll
        for (int nt = 0; nt < 2; ++nt) {
            floatx4 a = (mt == 0) ? (nt == 0 ? acc00 : acc01)
                                  : (nt == 0 ? acc10 : acc11);
            int n = nt * 16 + n15;
            #pragma unroll
            for (int reg = 0; reg < 4; ++reg) {
                int p = third * 128 + wv * 32 + mt * 16 + quad * 4 + reg;
                if (p < NP && n < 27) {
                    float vout = a[reg] + cb[n];
                    if (n < 26) out[(size_t)(pbase + p) * 26 + n] = vout;
                    else        out[PRED_N + pbase + p] = vout;
                }
            }
        }
    }
}

// ---------------------------------------------------------------------------
extern "C" void kernel_launch(void* const* d_in, const int* in_sizes, int n_in,
                              void* d_out, int out_size, void* d_ws, size_t ws_size,
                              hipStream_t stream) {
    const float* temporal = (const float*)d_in[0];
    const float* objf     = (const float*)d_in[1];
    const float* fq       = (const float*)d_in[2];
    const float* sa_in_w  = (const float*)d_in[3];
    const float* sa_in_b  = (const float*)d_in[4];
    const float* sa_out_w = (const float*)d_in[5];
    const float* sa_out_b = (const float*)d_in[6];
    const float* ca_in_w  = (const float*)d_in[7];
    const float* ca_in_b  = (const float*)d_in[8];
    const float* ca_out_w = (const float*)d_in[9];
    const float* ca_out_b = (const float*)d_in[10];
    const float* ff1_w    = (const float*)d_in[11];
    const float* ff1_b    = (const float*)d_in[12];
    const float* ff2_w    = (const float*)d_in[13];
    const float* ff2_b    = (const float*)d_in[14];
    const float* n1_w     = (const float*)d_in[15];
    const float* n1_b     = (const float*)d_in[16];
    const float* n2_w     = (const float*)d_in[17];
    const float* n2_b     = (const float*)d_in[18];
    const float* n3_w     = (const float*)d_in[19];
    const float* n3_b     = (const float*)d_in[20];
    const float* norm_w   = (const float*)d_in[21];
    const float* norm_b   = (const float*)d_in[22];
    const float* pe1_w    = (const float*)d_in[23];
    const float* pe1_b    = (const float*)d_in[24];
    const float* pe2_w    = (const float*)d_in[25];
    const float* pe2_b    = (const float*)d_in[26];
    const float* pred_w   = (const float*)d_in[27];
    const float* pred_b   = (const float*)d_in[28];
    const float* ex_w     = (const float*)d_in[29];
    const float* ex_b     = (const float*)d_in[30];

    // ---- workspace (floats), total 2,916,384 ~= 11.7 MB ----
    float* ws   = (float*)d_ws;
    float* x1   = ws;                    // 40960
    float* x2   = ws + 40960;            // 40960
    float* x3   = ws + 81920;            // 40960
    float* qkvp = ws + 122880;           // 4 x 122880
    float* qp   = ws + 614400;           // 4 x 40960
    float* yp   = ws + 778240;           // 8 x 40960
    float* ffp  = ws + 1105920;          // 2 x 163840
    float* kvb  = ws + 1433600;          // [zk2][l2][160][1024]
    float* SOp  = ws + 2088960;          // [zk2][320][1024]
    float* cpb  = ws + 2744320;          // 4 x 40960
    unsigned short* Mbf = (unsigned short*)(ws + 2908160);  // 16384 ushort
    float* cb   = ws + 2916352;          // 32
    float* out  = (float*)d_out;

    k_prep<<<657, 256, 0, stream>>>(objf, temporal, pe1_w, ca_in_w,
                                    pe2_w, pe2_b, pred_w, pred_b, ex_w, ex_b,
                                    SOp, kvb, Mbf, cb);
    for (int l = 0; l < 2; ++l) {
        if (l == 0) {
            k_gemm<<<dim3(12, 5, 4), 256, 0, stream>>>(
                fq, HD, XM_FQ, nullptr, 0, 0, nullptr, nullptr, nullptr,
                nullptr, nullptr, nullptr, 0, 0,
                sa_in_w, HD, qkvp, 1536, 122880, 128);
        } else {
            // LN3(l0) prologue: x3 = LN(x2 + 8 FF2 partials + ff2_b0; n3_0)
            k_gemm<<<dim3(12, 10, 4), 256, 0, stream>>>(
                x2, HD, XM_LN, yp, 8, 40960, ff2_b, n3_w, n3_b,
                nullptr, nullptr, x3, 0, 0,
                sa_in_w + 786432, HD, qkvp, 1536, 122880, 128);
        }
        k_attnsa_proj<<<256, 256, 0, stream>>>(l, qkvp, sa_in_b,
                                               sa_out_w + (size_t)l * 262144, yp);
        // LN1 prologue + CA-Q
        k_gemm<<<dim3(4, 10, 4), 256, 0, stream>>>(
            (l == 0 ? fq : x3), HD, XM_LN, yp, 4, 40960,
            sa_out_b + l * HD, n1_w + l * HD, n1_b + l * HD,
            nullptr, nullptr, x1, (l == 0 ? FH : 0), 0,
            ca_in_w + (size_t)l * 786432, HD, qp, HD, 40960, 128);
        k_attnca_proj<<<256, 256, 0, stream>>>(l, qp, kvb, ca_in_b,
                                               ca_out_w + (size_t)l * 262144, yp);
        // LN2 prologue + FF1
        k_gemm<<<dim3(16, 10, 2), 256, 0, stream>>>(
            x1, HD, XM_LN, yp, 4, 40960,
            ca_out_b + l * HD, n2_w + l * HD, n2_b + l * HD,
            nullptr, nullptr, x2, 0, 0,
            ff1_w + (size_t)l * 1048576, HD, ffp, FFD, 163840, 256);
        // FF2 with gelu-combine staging (2 FF1 partials)
        k_gemm<<<dim3(4, 5, 8), 256, 0, stream>>>(
            ffp, FFD, XM_GELU, nullptr, 0, 0, ff1_b + l * FFD,
            nullptr, nullptr, nullptr, nullptr, nullptr, 0, 163840,
            ff2_w + (size_t)l * 1048576, FFD, yp, HD, 40960, 256);
    }
    // LN3(l1)+final LN prologue, then ctx projection
    k_gemm<<<dim3(4, 10, 4), 256, 0, stream>>>(
        x2, HD, XM_LN2, yp, 8, 40960, ff2_b + HD, n3_w + HD, n3_b + HD,
        norm_w, norm_b, nullptr, 0, 0,
        pe1_w + 1024, 1536, cpb, HD, 40960, 128);
    k_pair<<<240, 256, 0, stream>>>(SOp, cpb, pe1_b, Mbf, cb, out);
}

// Round 7
// 381.035 us; speedup vs baseline: 4.0995x; 1.0905x over previous
//
#include <hip/hip_runtime.h>
#include <math.h>

// H=512, heads=8, dh=64, L=2, FF=2048, B=16, Fh=5, Tmem=10, Nobj=20, P=380.
#define HD 512
#define FFD 2048
#define FH 5
#define TM 10
#define NO 20
#define NP 380
#define PRED_N 790400   // 16*5*380*26

#define XM_PLAIN 0
#define XM_GELU  1
#define XM_FQ    2
#define XM_LN    3
#define XM_LN2   4

typedef short bf16x8 __attribute__((ext_vector_type(8)));
typedef float floatx4 __attribute__((ext_vector_type(4)));

__device__ __forceinline__ float gelu_f(float v) {
    return 0.5f * v * (1.0f + erff(v * 0.70710678118654752440f));
}
__device__ __forceinline__ unsigned short f2bf(float x) {
    unsigned int u = __float_as_uint(x);
    u = (u + 0x7FFFu + ((u >> 16) & 1u)) >> 16;   // RNE
    return (unsigned short)u;
}

// ---------------------------------------------------------------------------
// Tiled GEMM body, software-pipelined: W/X chunk k+1 prefetched into registers
// before compute of chunk k. Block tile RT x 128 (RT=16, RT=8 LN modes),
// K-chunk 64. Wt transposed stride 129 (stores 2-way free, reads conflict-free).
// lds floats: non-LN 9280 (37.1KB, 4 blk/CU), LN 12352 (49.4KB, 3 blk/CU).
// ---------------------------------------------------------------------------
template <int XMODE>
__device__ __forceinline__ void gemm_body(
    int bx, int by, int bz,
    const float* __restrict__ X, int ldx,
    const float* __restrict__ parts, int np, int pzstr,
    const float* __restrict__ bo,
    const float* __restrict__ lw, const float* __restrict__ lb,
    const float* __restrict__ fw, const float* __restrict__ fb,
    float* __restrict__ xout, int xmod, int gps,
    const float* __restrict__ W, int ldw,
    float* __restrict__ Y, int ldy, int zyoff,
    int Klen, float* lds)
{
    float* Wt = lds;            // 8256
    float* Xs = lds + 8256;     // 1024 (non-LN) or 4096 (LN)
    const int RT = (XMODE >= XM_LN) ? 8 : 16;
    int t = threadIdx.x;
    int nb = bx * 128;
    int r0 = by * RT;
    int kbase = bz * Klen;
    float* Yb = Y + (size_t)bz * zyoff;
    int c = t & 31, rg = t >> 5, scs = t >> 4, q = t & 15;

    if (XMODE >= XM_LN) {
        int rl = t >> 5;
        int r  = r0 + rl;
        int c0 = (t & 31) * 16;
        int rr = xmod ? (r % xmod) : r;
        float v[16];
        #pragma unroll
        for (int u = 0; u < 16; u += 4) {
            float4 a = *(const float4*)(X + (size_t)rr * ldx + c0 + u);
            float4 bb = *(const float4*)(bo + c0 + u);
            float vx = a.x + bb.x, vy = a.y + bb.y, vz = a.z + bb.z, vw = a.w + bb.w;
            for (int zz = 0; zz < np; ++zz) {
                float4 p = *(const float4*)(parts + (size_t)zz * pzstr + (size_t)r * HD + c0 + u);
                vx += p.x; vy += p.y; vz += p.z; vw += p.w;
            }
            v[u] = vx; v[u + 1] = vy; v[u + 2] = vz; v[u + 3] = vw;
        }
        float s1 = 0, s2 = 0;
        #pragma unroll
        for (int u = 0; u < 16; ++u) { s1 += v[u]; s2 += v[u] * v[u]; }
        #pragma unroll
        for (int o = 16; o > 0; o >>= 1) {
            s1 += __shfl_down(s1, o, 32);
            s2 += __shfl_down(s2, o, 32);
        }
        s1 = __shfl(s1, 0, 32); s2 = __shfl(s2, 0, 32);
        float mean = s1 * (1.0f / HD);
        float rstd = rsqrtf(s2 * (1.0f / HD) - mean * mean + 1e-5f);
        #pragma unroll
        for (int u = 0; u < 16; ++u)
            v[u] = (v[u] - mean) * rstd * lw[c0 + u] + lb[c0 + u];
        if (xout && bz == 0 && bx == 0) {
            #pragma unroll
            for (int u = 0; u < 16; u += 4)
                *(float4*)(xout + (size_t)r * HD + c0 + u) =
                    make_float4(v[u], v[u + 1], v[u + 2], v[u + 3]);
        }
        if (XMODE == XM_LN2) {
            float t1 = 0, t2 = 0;
            #pragma unroll
            for (int u = 0; u < 16; ++u) { t1 += v[u]; t2 += v[u] * v[u]; }
            #pragma unroll
            for (int o = 16; o > 0; o >>= 1) {
                t1 += __shfl_down(t1, o, 32);
                t2 += __shfl_down(t2, o, 32);
            }
            t1 = __shfl(t1, 0, 32); t2 = __shfl(t2, 0, 32);
            float m2 = t1 * (1.0f / HD);
            float rs2 = rsqrtf(t2 * (1.0f / HD) - m2 * m2 + 1e-5f);
            #pragma unroll
            for (int u = 0; u < 16; ++u)
                v[u] = (v[u] - m2) * rs2 * fw[c0 + u] + fb[c0 + u];
        }
        #pragma unroll
        for (int u = 0; u < 16; u += 4)
            *(float4*)(Xs + rl * HD + c0 + u) =
                make_float4(v[u], v[u + 1], v[u + 2], v[u + 3]);
        __syncthreads();
    }

    float a00 = 0, a01 = 0, a02 = 0, a03 = 0;
    float a10 = 0, a11 = 0, a12 = 0, a13 = 0;

    int nch = Klen >> 6;
    float4 wreg[8];
    float4 xra, xrb, xrc;
    {
        int kg = kbase;
        #pragma unroll
        for (int p = 0; p < 8; ++p)
            wreg[p] = *(const float4*)(W + (size_t)(nb + scs + p * 16) * ldw + kg + q * 4);
        if (XMODE == XM_PLAIN) {
            xra = *(const float4*)(X + (size_t)(r0 + scs) * ldx + kg + q * 4);
        } else if (XMODE == XM_FQ) {
            xra = *(const float4*)(X + (size_t)((r0 + scs) % FH) * ldx + kg + q * 4);
        } else if (XMODE == XM_GELU) {
            const float* p0 = X + (size_t)(r0 + scs) * ldx + kg + q * 4;
            xra = *(const float4*)p0;
            xrb = *(const float4*)(p0 + gps);
            xrc = *(const float4*)(bo + kg + q * 4);
        }
    }

    for (int ch = 0; ch < nch; ++ch) {
        if (ch) __syncthreads();
        if (XMODE <= XM_FQ) {
            float4 xv;
            if (XMODE == XM_GELU) {
                xv.x = gelu_f(xra.x + xrb.x + xrc.x);
                xv.y = gelu_f(xra.y + xrb.y + xrc.y);
                xv.z = gelu_f(xra.z + xrb.z + xrc.z);
                xv.w = gelu_f(xra.w + xrb.w + xrc.w);
            } else {
                xv = xra;
            }
            *(float4*)&Xs[scs * 64 + q * 4] = xv;
        }
        #pragma unroll
        for (int p = 0; p < 8; ++p) {
            int cc = scs + p * 16;
            Wt[(q * 4 + 0) * 129 + cc] = wreg[p].x;
            Wt[(q * 4 + 1) * 129 + cc] = wreg[p].y;
            Wt[(q * 4 + 2) * 129 + cc] = wreg[p].z;
            Wt[(q * 4 + 3) * 129 + cc] = wreg[p].w;
        }
        __syncthreads();
        if (ch + 1 < nch) {
            int kg = kbase + (ch + 1) * 64;
            #pragma unroll
            for (int p = 0; p < 8; ++p)
                wreg[p] = *(const float4*)(W + (size_t)(nb + scs + p * 16) * ldw + kg + q * 4);
            if (XMODE == XM_PLAIN) {
                xra = *(const float4*)(X + (size_t)(r0 + scs) * ldx + kg + q * 4);
            } else if (XMODE == XM_FQ) {
                xra = *(const float4*)(X + (size_t)((r0 + scs) % FH) * ldx + kg + q * 4);
            } else if (XMODE == XM_GELU) {
                const float* p0 = X + (size_t)(r0 + scs) * ldx + kg + q * 4;
                xra = *(const float4*)p0;
                xrb = *(const float4*)(p0 + gps);
                xrc = *(const float4*)(bo + kg + q * 4);
            }
        }
        if (RT == 16) {
            const float* xr0 = &Xs[(rg * 2 + 0) * 64];
            const float* xr1 = &Xs[(rg * 2 + 1) * 64];
            #pragma unroll
            for (int k4 = 0; k4 < 16; ++k4) {
                float4 x0 = *(const float4*)(xr0 + k4 * 4);
                float4 x1 = *(const float4*)(xr1 + k4 * 4);
                const float* x0p = (const float*)&x0;
                const float* x1p = (const float*)&x1;
                #pragma unroll
                for (int i = 0; i < 4; ++i) {
                    const float* wrow = &Wt[(k4 * 4 + i) * 129 + c];
                    float w0 = wrow[0], w1 = wrow[32], w2 = wrow[64], w3 = wrow[96];
                    float xi0 = x0p[i], xi1 = x1p[i];
                    a00 = fmaf(xi0, w0, a00); a01 = fmaf(xi0, w1, a01);
                    a02 = fmaf(xi0, w2, a02); a03 = fmaf(xi0, w3, a03);
                    a10 = fmaf(xi1, w0, a10); a11 = fmaf(xi1, w1, a11);
                    a12 = fmaf(xi1, w2, a12); a13 = fmaf(xi1, w3, a13);
                }
            }
        } else {
            const float* xr0 = &Xs[rg * HD + kbase + ch * 64];
            #pragma unroll
            for (int k4 = 0; k4 < 16; ++k4) {
                float4 x0 = *(const float4*)(xr0 + k4 * 4);
                const float* x0p = (const float*)&x0;
                #pragma unroll
                for (int i = 0; i < 4; ++i) {
                    const float* wrow = &Wt[(k4 * 4 + i) * 129 + c];
                    float xi0 = x0p[i];
                    a00 = fmaf(xi0, wrow[0],  a00);
                    a01 = fmaf(xi0, wrow[32], a01);
                    a02 = fmaf(xi0, wrow[64], a02);
                    a03 = fmaf(xi0, wrow[96], a03);
                }
            }
        }
    }
    if (RT == 16) {
        float* yr = Yb + (size_t)(r0 + rg * 2) * ldy + nb + c;
        yr[0] = a00; yr[32] = a01; yr[64] = a02; yr[96] = a03;
        yr += ldy;
        yr[0] = a10; yr[32] = a11; yr[64] = a12; yr[96] = a13;
    } else {
        float* yr = Yb + (size_t)(r0 + rg) * ldy + nb + c;
        yr[0] = a00; yr[32] = a01; yr[64] = a02; yr[96] = a03;
    }
}

template <int XMODE>
__global__ __launch_bounds__(256) void k_gemm(
    const float* __restrict__ X, int ldx,
    const float* __restrict__ parts, int np, int pzstr,
    const float* __restrict__ bo,
    const float* __restrict__ lw, const float* __restrict__ lb,
    const float* __restrict__ fw, const float* __restrict__ fb,
    float* __restrict__ xout, int xmod, int gps,
    const float* __restrict__ W, int ldw,
    float* __restrict__ Y, int ldy, int zyoff, int Klen)
{
    __shared__ float lds[(XMODE >= XM_LN) ? 12352 : 9280];
    gemm_body<XMODE>(blockIdx.x, blockIdx.y, blockIdx.z, X, ldx, parts, np, pzstr,
                     bo, lw, lb, fw, fb, xout, xmod, gps, W, ldw, Y, ldy, zyoff,
                     Klen, lds);
}

// ---------------------------------------------------------------------------
// M = pe2^T @ [pred;ex]^T stored as bf16 MFMA B-frags (R5-verified) + cb.
// ---------------------------------------------------------------------------
__device__ void mprep(int m, const float* __restrict__ pe2_w, const float* __restrict__ pe2_b,
                      const float* __restrict__ pred_w, const float* __restrict__ pred_b,
                      const float* __restrict__ ex_w, const float* __restrict__ ex_b,
                      unsigned short* __restrict__ Mbf, float* __restrict__ cb, float* lds)
{
    int t = threadIdx.x;
    if (m < 16) {
        int dl = t & 31, ec = t >> 5;
        int d = m * 32 + dl;
        float acc[27];
        #pragma unroll
        for (int k = 0; k < 27; ++k) acc[k] = 0.f;
        for (int e = ec * 64; e < ec * 64 + 64; ++e) {
            float wv = pe2_w[(size_t)e * HD + d];
            #pragma unroll
            for (int k = 0; k < 26; ++k) acc[k] = fmaf(wv, pred_w[k * HD + e], acc[k]);
            acc[26] = fmaf(wv, ex_w[e], acc[26]);
        }
        #pragma unroll
        for (int k = 0; k < 27; ++k) lds[(ec * 32 + dl) * 27 + k] = acc[k];
        __syncthreads();
        for (int idx = t; idx < 1024; idx += 256) {
            int dl2 = idx >> 5, k = idx & 31;
            float s = 0.f;
            if (k < 27) {
                #pragma unroll
                for (int e = 0; e < 8; ++e) s += lds[(e * 32 + dl2) * 27 + k];
            }
            int quad = dl2 >> 3, j = dl2 & 7;
            int nt = k >> 4, n15 = k & 15;
            int lane = quad * 16 + n15;
            Mbf[((size_t)(m * 2 + nt) * 64 + lane) * 8 + j] = f2bf(s);
        }
    } else {
        int g = t >> 3, li = t & 7;
        if (g < 27) {
            const float* wo = (g < 26) ? (pred_w + g * HD) : ex_w;
            float a = 0.f;
            for (int e = li; e < HD; e += 8) a += pe2_b[e] * wo[e];
            a += __shfl_down(a, 4, 8);
            a += __shfl_down(a, 2, 8);
            a += __shfl_down(a, 1, 8);
            if (li == 0) cb[g] = a + ((g < 26) ? pred_b[g] : ex_b[0]);
        }
    }
}

// ---------------------------------------------------------------------------
// Merged prep: SO gemm [0,320) | CA-KV gemm [320,640) | M fold [640,657).
// ---------------------------------------------------------------------------
__global__ __launch_bounds__(256) void k_prep(
    const float* __restrict__ objf, const float* __restrict__ temporal,
    const float* __restrict__ pe1_w, const float* __restrict__ ca_in_w,
    const float* __restrict__ pe2_w, const float* __restrict__ pe2_b,
    const float* __restrict__ pred_w, const float* __restrict__ pred_b,
    const float* __restrict__ ex_w, const float* __restrict__ ex_b,
    float* __restrict__ SOp, float* __restrict__ kvb,
    unsigned short* __restrict__ Mbf, float* __restrict__ cb)
{
    __shared__ float lds[9280];
    int blk = blockIdx.x;
    if (blk < 320) {
        int zw = blk & 1, zk = (blk >> 1) & 1, ct = (blk >> 2) & 3, y = blk >> 4;
        gemm_body<XM_PLAIN>(ct, y, zk, objf, HD, nullptr, 0, 0,
                            nullptr, nullptr, nullptr, nullptr, nullptr,
                            nullptr, 0, 0,
                            pe1_w + zw * 512, 1536,
                            SOp + zw * 512, 1024, 327680, 256, lds);
    } else if (blk < 640) {
        int s = blk - 320;
        int ct = s & 7, l = (s >> 3) & 1, zk = (s >> 4) & 1, y = s >> 5;
        gemm_body<XM_PLAIN>(ct, y, zk, temporal, HD, nullptr, 0, 0,
                            nullptr, nullptr, nullptr, nullptr, nullptr,
                            nullptr, 0, 0,
                            ca_in_w + (size_t)(l * 1536 + 512) * HD, HD,
                            kvb + (size_t)((zk * 2 + l) * 160) * 1024, 1024, 0, 256, lds);
    } else {
        mprep(blk - 640, pe2_w, pe2_b, pred_w, pred_b, ex_w, ex_b, Mbf, cb, lds);
    }
}

// ---------------------------------------------------------------------------
// Fused SA + out-proj, head-sliced: block (b, ct, zk) computes attention for
// heads {2zk, 2zk+1} only (the K-slice its proj needs). 256 blocks.
// W chunk-0 prefetched into registers BEFORE the attention phase.
// ---------------------------------------------------------------------------
__global__ __launch_bounds__(256) void k_attnsa_proj(
    int l, const float* __restrict__ qkvp, const float* __restrict__ in_b,
    const float* __restrict__ Wout, float* __restrict__ yp)
{
    __shared__ float lds[8896];
    int bi = blockIdx.x;
    int b = bi >> 4, ct = (bi >> 2) & 3, zk = bi & 3;
    int t = threadIdx.x;
    float* qkv = lds;          // [3][5][128]
    float* sc  = lds + 1920;   // 50
    float* aw  = lds + 1984;   // 50
    float* ao  = lds + 8256;   // [5][128]
    float* Wt  = lds;          // proj phase (attn scratch dead)
    int col0 = zk * 128;
    int c = t & 31, rg = t >> 5, scs = t >> 4, q = t & 15;
    int nb = ct * 128;

    float4 wreg[8];
    #pragma unroll
    for (int p = 0; p < 8; ++p)
        wreg[p] = *(const float4*)(Wout + (size_t)(nb + scs + p * 16) * HD + col0 + q * 4);

    for (int idx = t; idx < 480; idx += 256) {
        int m = idx / 160, r = idx - m * 160;
        int tok = r >> 5, c4 = (r & 31) * 4;
        int col = m * HD + col0 + c4;
        size_t o = (size_t)(b * FH + tok) * 1536 + col;
        float4 v = *(const float4*)(in_b + l * 1536 + col);
        #pragma unroll
        for (int z = 0; z < 4; ++z) {
            float4 p = *(const float4*)(qkvp + (size_t)z * 122880 + o);
            v.x += p.x; v.y += p.y; v.z += p.z; v.w += p.w;
        }
        *(float4*)(qkv + (m * FH + tok) * 128 + c4) = v;
    }
    __syncthreads();
    if (t < 50) {
        int hh = t / 25, r = t - hh * 25, tq = r / 5, tu = r % 5;
        float s = 0;
        for (int d = 0; d < 64; ++d)
            s += qkv[tq * 128 + hh * 64 + d] * qkv[(FH + tu) * 128 + hh * 64 + d];
        sc[t] = s * 0.125f;
    }
    __syncthreads();
    if (t < 10) {
        int base = (t / 5) * 25 + (t % 5) * 5;
        float mx = -1e30f;
        for (int u = 0; u < 5; ++u) mx = fmaxf(mx, sc[base + u]);
        float e[5], sm = 0;
        for (int u = 0; u < 5; ++u) { e[u] = expf(sc[base + u] - mx); sm += e[u]; }
        for (int u = 0; u < 5; ++u) aw[base + u] = e[u] / sm;
    }
    __syncthreads();
    for (int idx = t; idx < 640; idx += 256) {
        int tok = idx >> 7, cc = idx & 127, hh = cc >> 6;
        float s = 0;
        #pragma unroll
        for (int u = 0; u < 5; ++u)
            s += aw[hh * 25 + tok * 5 + u] * qkv[(2 * FH + u) * 128 + cc];
        ao[tok * 128 + cc] = s;
    }
    __syncthreads();

    float a0 = 0, a1 = 0, a2 = 0, a3 = 0;
    for (int ch = 0; ch < 2; ++ch) {
        if (ch) __syncthreads();
        #pragma unroll
        for (int p = 0; p < 8; ++p) {
            int cc = scs + p * 16;
            Wt[(q * 4 + 0) * 129 + cc] = wreg[p].x;
            Wt[(q * 4 + 1) * 129 + cc] = wreg[p].y;
            Wt[(q * 4 + 2) * 129 + cc] = wreg[p].z;
            Wt[(q * 4 + 3) * 129 + cc] = wreg[p].w;
        }
        __syncthreads();
        if (ch == 0) {
            #pragma unroll
            for (int p = 0; p < 8; ++p)
                wreg[p] = *(const float4*)(Wout + (size_t)(nb + scs + p * 16) * HD + col0 + 64 + q * 4);
        }
        if (rg < FH) {
            const float* xr = ao + rg * 128 + ch * 64;
            #pragma unroll
            for (int k4 = 0; k4 < 16; ++k4) {
                float4 xv = *(const float4*)(xr + k4 * 4);
                #pragma unroll
                for (int i = 0; i < 4; ++i) {
                    const float* wr = &Wt[(k4 * 4 + i) * 129 + c];
                    float x = ((const float*)&xv)[i];
                    a0 = fmaf(x, wr[0],  a0); a1 = fmaf(x, wr[32], a1);
                    a2 = fmaf(x, wr[64], a2); a3 = fmaf(x, wr[96], a3);
                }
            }
        }
    }
    if (rg < FH) {
        float* yr = yp + (size_t)zk * 40960 + (size_t)(b * FH + rg) * HD + nb + c;
        yr[0] = a0; yr[32] = a1; yr[64] = a2; yr[96] = a3;
    }
}

// ---------------------------------------------------------------------------
// Fused CA + out-proj, head-sliced. Block (b, ct, zk): 256 blocks.
// ---------------------------------------------------------------------------
__global__ __launch_bounds__(256) void k_attnca_proj(
    int l, const float* __restrict__ qp, const float* __restrict__ kvb,
    const float* __restrict__ in_b, const float* __restrict__ Wout,
    float* __restrict__ yp)
{
    __shared__ float lds[8896];
    int bi = blockIdx.x;
    int b = bi >> 4, ct = (bi >> 2) & 3, zk = bi & 3;
    int t = threadIdx.x;
    float* qs = lds;            // [5][128]
    float* kl = lds + 640;      // [10][128]
    float* vl = lds + 1920;     // [10][128]
    float* sc = lds + 3200;     // 100
    float* aw = lds + 3328;     // 100
    float* ao = lds + 8256;     // [5][128]
    float* Wt = lds;            // proj phase
    const float* bb = in_b + l * 1536;
    int col0 = zk * 128;
    int c = t & 31, rg = t >> 5, scs = t >> 4, q = t & 15;
    int nb = ct * 128;

    float4 wreg[8];
    #pragma unroll
    for (int p = 0; p < 8; ++p)
        wreg[p] = *(const float4*)(Wout + (size_t)(nb + scs + p * 16) * HD + col0 + q * 4);

    if (t < 160) {
        int tok = t >> 5, c4 = (t & 31) * 4;
        size_t o = (size_t)(b * FH + tok) * HD + col0 + c4;
        float4 v = *(const float4*)(bb + col0 + c4);
        #pragma unroll
        for (int z = 0; z < 4; ++z) {
            float4 p = *(const float4*)(qp + (size_t)z * 40960 + o);
            v.x += p.x; v.y += p.y; v.z += p.z; v.w += p.w;
        }
        *(float4*)(qs + tok * 128 + c4) = v;
    }
    for (int idx = t; idx < 320; idx += 256) {
        int u = idx >> 5, c4 = (idx & 31) * 4;
        size_t base = (size_t)(l * 160 + b * TM + u) * 1024;
        float4 k0 = *(const float4*)(kvb + base + col0 + c4);
        float4 k1 = *(const float4*)(kvb + 327680 + base + col0 + c4);
        float4 bk = *(const float4*)(bb + 512 + col0 + c4);
        *(float4*)(kl + u * 128 + c4) =
            make_float4(k0.x + k1.x + bk.x, k0.y + k1.y + bk.y,
                        k0.z + k1.z + bk.z, k0.w + k1.w + bk.w);
        float4 v0 = *(const float4*)(kvb + base + 512 + col0 + c4);
        float4 v1 = *(const float4*)(kvb + 327680 + base + 512 + col0 + c4);
        float4 bv = *(const float4*)(bb + 1024 + col0 + c4);
        *(float4*)(vl + u * 128 + c4) =
            make_float4(v0.x + v1.x + bv.x, v0.y + v1.y + bv.y,
                        v0.z + v1.z + bv.z, v0.w + v1.w + bv.w);
    }
    __syncthreads();
    if (t < 100) {
        int hh = t / 50, r = t - hh * 50, tq = r / 10, tu = r % 10;
        float s = 0;
        for (int d = 0; d < 64; ++d)
            s += qs[tq * 128 + hh * 64 + d] * kl[tu * 128 + hh * 64 + d];
        sc[t] = s * 0.125f;
    }
    __syncthreads();
    if (t < 10) {
        int base = (t / 5) * 50 + (t % 5) * 10;
        float mx = -1e30f;
        for (int u = 0; u < TM; ++u) mx = fmaxf(mx, sc[base + u]);
        float e[TM], sm = 0;
        for (int u = 0; u < TM; ++u) { e[u] = expf(sc[base + u] - mx); sm += e[u]; }
        for (int u = 0; u < TM; ++u) aw[base + u] = e[u] / sm;
    }
    __syncthreads();
    for (int idx = t; idx < 640; idx += 256) {
        int tok = idx >> 7, cc = idx & 127, hh = cc >> 6;
        float s = 0;
        #pragma unroll
        for (int u = 0; u < TM; ++u)
            s += aw[hh * 50 + tok * 10 + u] * vl[u * 128 + cc];
        ao[tok * 128 + cc] = s;
    }
    __syncthreads();

    float a0 = 0, a1 = 0, a2 = 0, a3 = 0;
    for (int ch = 0; ch < 2; ++ch) {
        if (ch) __syncthreads();
        #pragma unroll
        for (int p = 0; p < 8; ++p) {
            int cc = scs + p * 16;
            Wt[(q * 4 + 0) * 129 + cc] = wreg[p].x;
            Wt[(q * 4 + 1) * 129 + cc] = wreg[p].y;
            Wt[(q * 4 + 2) * 129 + cc] = wreg[p].z;
            Wt[(q * 4 + 3) * 129 + cc] = wreg[p].w;
        }
        __syncthreads();
        if (ch == 0) {
            #pragma unroll
            for (int p = 0; p < 8; ++p)
                wreg[p] = *(const float4*)(Wout + (size_t)(nb + scs + p * 16) * HD + col0 + 64 + q * 4);
        }
        if (rg < FH) {
            const float* xr = ao + rg * 128 + ch * 64;
            #pragma unroll
            for (int k4 = 0; k4 < 16; ++k4) {
                float4 xv = *(const float4*)(xr + k4 * 4);
                #pragma unroll
                for (int i = 0; i < 4; ++i) {
                    const float* wr = &Wt[(k4 * 4 + i) * 129 + c];
                    float x = ((const float*)&xv)[i];
                    a0 = fmaf(x, wr[0],  a0); a1 = fmaf(x, wr[32], a1);
                    a2 = fmaf(x, wr[64], a2); a3 = fmaf(x, wr[96], a3);
                }
            }
        }
    }
    if (rg < FH) {
        float* yr = yp + (size_t)zk * 40960 + (size_t)(b * FH + rg) * HD + nb + c;
        yr[0] = a0; yr[32] = a1; yr[64] = a2; yr[96] = a3;
    }
}

// ---------------------------------------------------------------------------
// Pair head via MFMA (R5-verified layouts). grid = 16*5*3 = 240.
// ---------------------------------------------------------------------------
__global__ __launch_bounds__(256) void k_pair(
    const float* __restrict__ SOp, const float* __restrict__ cpb,
    const float* __restrict__ pe1_b,
    const unsigned short* __restrict__ Mbf, const float* __restrict__ cb,
    float* __restrict__ out)
{
    __shared__ float lds[14964];
    int blk = blockIdx.x;
    int third = blk % 3, bf = blk / 3;
    int b = bf / FH, f = bf % FH;
    int t = threadIdx.x;
    int wv = t >> 6, lane = t & 63;
    int quad = lane >> 4, n15 = lane & 15;
    int i0 = (third == 0) ? 0 : (third == 1 ? 6 : 13);

    for (int idx = t; idx < 29 * 128; idx += 256) {
        int row = idx >> 7, c4 = (idx & 127) << 2;
        float4 v;
        if (row < 8) {
            int i = i0 + row; if (i > 19) i = 19;
            size_t o = (size_t)(b * NO + i) * 1024 + c4;
            float4 p0 = *(const float4*)(SOp + o);
            float4 p1 = *(const float4*)(SOp + 327680 + o);
            v = make_float4(p0.x + p1.x, p0.y + p1.y, p0.z + p1.z, p0.w + p1.w);
        } else if (row < 28) {
            int j = row - 8;
            size_t o = (size_t)(b * NO + j) * 1024 + 512 + c4;
            float4 p0 = *(const float4*)(SOp + o);
            float4 p1 = *(const float4*)(SOp + 327680 + o);
            v = make_float4(p0.x + p1.x, p0.y + p1.y, p0.z + p1.z, p0.w + p1.w);
        } else {
            size_t o = (size_t)(b * FH + f) * HD + c4;
            float4 s = *(const float4*)(cpb + o);
            #pragma unroll
            for (int z = 1; z < 4; ++z) {
                float4 p = *(const float4*)(cpb + (size_t)z * 40960 + o);
                s.x += p.x; s.y += p.y; s.z += p.z; s.w += p.w;
            }
            float4 pb = *(const float4*)(pe1_b + c4);
            v = make_float4(s.x + pb.x, s.y + pb.y, s.z + pb.z, s.w + pb.w);
        }
        *(float4*)(lds + row * 516 + c4) = v;
    }
    __syncthreads();

    floatx4 acc00 = {0,0,0,0}, acc01 = {0,0,0,0}, acc10 = {0,0,0,0}, acc11 = {0,0,0,0};
    for (int ks = 0; ks < 16; ++ks) {
        bf16x8 b0 = *(const bf16x8*)(Mbf + ((size_t)(ks * 2 + 0) * 64 + lane) * 8);
        bf16x8 b1 = *(const bf16x8*)(Mbf + ((size_t)(ks * 2 + 1) * 64 + lane) * 8);
        #pragma unroll
        for (int mt = 0; mt < 2; ++mt) {
            int p = third * 128 + wv * 32 + mt * 16 + n15;
            bf16x8 afr = {0, 0, 0, 0, 0, 0, 0, 0};
            if (p < NP) {
                int i = p / 19, j0 = p % 19;
                int j = j0 + (j0 >= i ? 1 : 0);
                int dof = ks * 32 + quad * 8;
                const float* Sr = lds + (i - i0) * 516 + dof;
                const float* Or = lds + (8 + j) * 516 + dof;
                const float* Cr = lds + 28 * 516 + dof;
                float4 sa = *(const float4*)Sr, sb = *(const float4*)(Sr + 4);
                float4 oa = *(const float4*)Or, ob = *(const float4*)(Or + 4);
                float4 ca = *(const float4*)Cr, cc = *(const float4*)(Cr + 4);
                union { unsigned short u[8]; bf16x8 v8; } pk;
                pk.u[0] = f2bf(gelu_f(sa.x + oa.x + ca.x));
                pk.u[1] = f2bf(gelu_f(sa.y + oa.y + ca.y));
                pk.u[2] = f2bf(gelu_f(sa.z + oa.z + ca.z));
                pk.u[3] = f2bf(gelu_f(sa.w + oa.w + ca.w));
                pk.u[4] = f2bf(gelu_f(sb.x + ob.x + cc.x));
                pk.u[5] = f2bf(gelu_f(sb.y + ob.y + cc.y));
                pk.u[6] = f2bf(gelu_f(sb.z + ob.z + cc.z));
                pk.u[7] = f2bf(gelu_f(sb.w + ob.w + cc.w));
                afr = pk.v8;
            }
            if (mt == 0) {
                acc00 = __builtin_amdgcn_mfma_f32_16x16x32_bf16(afr, b0, acc00, 0, 0, 0);
                acc01 = __builtin_amdgcn_mfma_f32_16x16x32_bf16(afr, b1, acc01, 0, 0, 0);
            } else {
                acc10 = __builtin_amdgcn_mfma_f32_16x16x32_bf16(afr, b0, acc10, 0, 0, 0);
                acc11 = __builtin_amdgcn_mfma_f32_16x16x32_bf16(afr, b1, acc11, 0, 0, 0);
            }
        }
    }
    int pbase = (b * FH + f) * NP;
    #pragma unroll
    for (int mt = 0; mt < 2; ++mt) {
        #pragma unroll
        for (int nt = 0; nt < 2; ++nt) {
            floatx4 a = (mt == 0) ? (nt == 0 ? acc00 : acc01)
                                  : (nt == 0 ? acc10 : acc11);
            int n = nt * 16 + n15;
            #pragma unroll
            for (int reg = 0; reg < 4; ++reg) {
                int p = third * 128 + wv * 32 + mt * 16 + quad * 4 + reg;
                if (p < NP && n < 27) {
                    float vout = a[reg] + cb[n];
                    if (n < 26) out[(size_t)(pbase + p) * 26 + n] = vout;
                    else        out[PRED_N + pbase + p] = vout;
                }
            }
        }
    }
}

// ---------------------------------------------------------------------------
extern "C" void kernel_launch(void* const* d_in, const int* in_sizes, int n_in,
                              void* d_out, int out_size, void* d_ws, size_t ws_size,
                              hipStream_t stream) {
    const float* temporal = (const float*)d_in[0];
    const float* objf     = (const float*)d_in[1];
    const float* fq       = (const float*)d_in[2];
    const float* sa_in_w  = (const float*)d_in[3];
    const float* sa_in_b  = (const float*)d_in[4];
    const float* sa_out_w = (const float*)d_in[5];
    const float* sa_out_b = (const float*)d_in[6];
    const float* ca_in_w  = (const float*)d_in[7];
    const float* ca_in_b  = (const float*)d_in[8];
    const float* ca_out_w = (const float*)d_in[9];
    const float* ca_out_b = (const float*)d_in[10];
    const float* ff1_w    = (const float*)d_in[11];
    const float* ff1_b    = (const float*)d_in[12];
    const float* ff2_w    = (const float*)d_in[13];
    const float* ff2_b    = (const float*)d_in[14];
    const float* n1_w     = (const float*)d_in[15];
    const float* n1_b     = (const float*)d_in[16];
    const float* n2_w     = (const float*)d_in[17];
    const float* n2_b     = (const float*)d_in[18];
    const float* n3_w     = (const float*)d_in[19];
    const float* n3_b     = (const float*)d_in[20];
    const float* norm_w   = (const float*)d_in[21];
    const float* norm_b   = (const float*)d_in[22];
    const float* pe1_w    = (const float*)d_in[23];
    const float* pe1_b    = (const float*)d_in[24];
    const float* pe2_w    = (const float*)d_in[25];
    const float* pe2_b    = (const float*)d_in[26];
    const float* pred_w   = (const float*)d_in[27];
    const float* pred_b   = (const float*)d_in[28];
    const float* ex_w     = (const float*)d_in[29];
    const float* ex_b     = (const float*)d_in[30];

    // ---- workspace (floats), total 2,916,384 ~= 11.7 MB ----
    float* ws   = (float*)d_ws;
    float* x1   = ws;                    // 40960
    float* x2   = ws + 40960;            // 40960
    float* x3   = ws + 81920;            // 40960
    float* qkvp = ws + 122880;           // 4 x 122880
    float* qp   = ws + 614400;           // 4 x 40960
    float* yp   = ws + 778240;           // 8 x 40960
    float* ffp  = ws + 1105920;          // 2 x 163840
    float* kvb  = ws + 1433600;          // [zk2][l2][160][1024]
    float* SOp  = ws + 2088960;          // [zk2][320][1024]
    float* cpb  = ws + 2744320;          // 4 x 40960
    unsigned short* Mbf = (unsigned short*)(ws + 2908160);  // 16384 ushort
    float* cb   = ws + 2916352;          // 32
    float* out  = (float*)d_out;

    k_prep<<<657, 256, 0, stream>>>(objf, temporal, pe1_w, ca_in_w,
                                    pe2_w, pe2_b, pred_w, pred_b, ex_w, ex_b,
                                    SOp, kvb, Mbf, cb);
    for (int l = 0; l < 2; ++l) {
        if (l == 0) {
            k_gemm<XM_FQ><<<dim3(12, 5, 4), 256, 0, stream>>>(
                fq, HD, nullptr, 0, 0, nullptr, nullptr, nullptr,
                nullptr, nullptr, nullptr, 0, 0,
                sa_in_w, HD, qkvp, 1536, 122880, 128);
        } else {
            k_gemm<XM_LN><<<dim3(12, 10, 4), 256, 0, stream>>>(
                x2, HD, yp, 8, 40960, ff2_b, n3_w, n3_b,
                nullptr, nullptr, x3, 0, 0,
                sa_in_w + 786432, HD, qkvp, 1536, 122880, 128);
        }
        k_attnsa_proj<<<256, 256, 0, stream>>>(l, qkvp, sa_in_b,
                                               sa_out_w + (size_t)l * 262144, yp);
        k_gemm<XM_LN><<<dim3(4, 10, 4), 256, 0, stream>>>(
            (l == 0 ? fq : x3), HD, yp, 4, 40960,
            sa_out_b + l * HD, n1_w + l * HD, n1_b + l * HD,
            nullptr, nullptr, x1, (l == 0 ? FH : 0), 0,
            ca_in_w + (size_t)l * 786432, HD, qp, HD, 40960, 128);
        k_attnca_proj<<<256, 256, 0, stream>>>(l, qp, kvb, ca_in_b,
                                               ca_out_w + (size_t)l * 262144, yp);
        k_gemm<XM_LN><<<dim3(16, 10, 2), 256, 0, stream>>>(
            x1, HD, yp, 4, 40960,
            ca_out_b + l * HD, n2_w + l * HD, n2_b + l * HD,
            nullptr, nullptr, x2, 0, 0,
            ff1_w + (size_t)l * 1048576, HD, ffp, FFD, 163840, 256);
        k_gemm<XM_GELU><<<dim3(4, 5, 8), 256, 0, stream>>>(
            ffp, FFD, nullptr, 0, 0, ff1_b + l * FFD,
            nullptr, nullptr, nullptr, nullptr, nullptr, 0, 163840,
            ff2_w + (size_t)l * 1048576, FFD, yp, HD, 40960, 256);
    }
    k_gemm<XM_LN2><<<dim3(4, 10, 4), 256, 0, stream>>>(
        x2, HD, yp, 8, 40960, ff2_b + HD, n3_w + HD, n3_b + HD,
        norm_w, norm_b, nullptr, 0, 0,
        pe1_w + 1024, 1536, cpb, HD, 40960, 128);
    k_pair<<<240, 256, 0, stream>>>(SOp, cpb, pe1_b, Mbf, cb, out);
}

// Round 8
// 368.346 us; speedup vs baseline: 4.2407x; 1.0345x over previous
//
#include <hip/hip_runtime.h>
#include <math.h>

// H=512, heads=8, dh=64, L=2, FF=2048, B=16, Fh=5, Tmem=10, Nobj=20, P=380.
#define HD 512
#define FFD 2048
#define FH 5
#define TM 10
#define NO 20
#define NP 380
#define PRED_N 790400   // 16*5*380*26

#define XM_PLAIN 0
#define XM_GELU  1
#define XM_FQ    2
#define XM_LN    3
#define XM_LN2   4

typedef short bf16x8 __attribute__((ext_vector_type(8)));
typedef float floatx4 __attribute__((ext_vector_type(4)));

__device__ __forceinline__ float gelu_f(float v) {
    return 0.5f * v * (1.0f + erff(v * 0.70710678118654752440f));
}
__device__ __forceinline__ unsigned short f2bf(float x) {
    unsigned int u = __float_as_uint(x);
    u = (u + 0x7FFFu + ((u >> 16) & 1u)) >> 16;   // RNE
    return (unsigned short)u;
}

// ---------------------------------------------------------------------------
// Tiled GEMM body, software-pipelined (W/X chunk k+1 prefetched to registers
// during compute of chunk k). Block tile RT x 128 (RT=16; RT=8 LN modes),
// K-chunk 64. Wt transposed stride 129 (stores 2-way free, reads conflict-free).
// ---------------------------------------------------------------------------
template <int XMODE>
__device__ __forceinline__ void gemm_body(
    int bx, int by, int bz,
    const float* __restrict__ X, int ldx,
    const float* __restrict__ parts, int np, int pzstr,
    const float* __restrict__ bo,
    const float* __restrict__ lw, const float* __restrict__ lb,
    const float* __restrict__ fw, const float* __restrict__ fb,
    float* __restrict__ xout, int xmod, int gps,
    const float* __restrict__ W, int ldw,
    float* __restrict__ Y, int ldy, int zyoff,
    int Klen, float* lds)
{
    float* Wt = lds;            // 8256
    float* Xs = lds + 8256;     // 1024 (non-LN) or 4096 (LN)
    const int RT = (XMODE >= XM_LN) ? 8 : 16;
    int t = threadIdx.x;
    int nb = bx * 128;
    int r0 = by * RT;
    int kbase = bz * Klen;
    float* Yb = Y + (size_t)bz * zyoff;
    int c = t & 31, rg = t >> 5, scs = t >> 4, q = t & 15;

    if (XMODE >= XM_LN) {
        int rl = t >> 5;
        int r  = r0 + rl;
        int c0 = (t & 31) * 16;
        int rr = xmod ? (r % xmod) : r;
        float v[16];
        #pragma unroll
        for (int u = 0; u < 16; u += 4) {
            float4 a = *(const float4*)(X + (size_t)rr * ldx + c0 + u);
            float4 bb = *(const float4*)(bo + c0 + u);
            float vx = a.x + bb.x, vy = a.y + bb.y, vz = a.z + bb.z, vw = a.w + bb.w;
            for (int zz = 0; zz < np; ++zz) {
                float4 p = *(const float4*)(parts + (size_t)zz * pzstr + (size_t)r * HD + c0 + u);
                vx += p.x; vy += p.y; vz += p.z; vw += p.w;
            }
            v[u] = vx; v[u + 1] = vy; v[u + 2] = vz; v[u + 3] = vw;
        }
        float s1 = 0, s2 = 0;
        #pragma unroll
        for (int u = 0; u < 16; ++u) { s1 += v[u]; s2 += v[u] * v[u]; }
        #pragma unroll
        for (int o = 16; o > 0; o >>= 1) {
            s1 += __shfl_down(s1, o, 32);
            s2 += __shfl_down(s2, o, 32);
        }
        s1 = __shfl(s1, 0, 32); s2 = __shfl(s2, 0, 32);
        float mean = s1 * (1.0f / HD);
        float rstd = rsqrtf(s2 * (1.0f / HD) - mean * mean + 1e-5f);
        #pragma unroll
        for (int u = 0; u < 16; ++u)
            v[u] = (v[u] - mean) * rstd * lw[c0 + u] + lb[c0 + u];
        if (xout && bz == 0 && bx == 0) {
            #pragma unroll
            for (int u = 0; u < 16; u += 4)
                *(float4*)(xout + (size_t)r * HD + c0 + u) =
                    make_float4(v[u], v[u + 1], v[u + 2], v[u + 3]);
        }
        if (XMODE == XM_LN2) {
            float t1 = 0, t2 = 0;
            #pragma unroll
            for (int u = 0; u < 16; ++u) { t1 += v[u]; t2 += v[u] * v[u]; }
            #pragma unroll
            for (int o = 16; o > 0; o >>= 1) {
                t1 += __shfl_down(t1, o, 32);
                t2 += __shfl_down(t2, o, 32);
            }
            t1 = __shfl(t1, 0, 32); t2 = __shfl(t2, 0, 32);
            float m2 = t1 * (1.0f / HD);
            float rs2 = rsqrtf(t2 * (1.0f / HD) - m2 * m2 + 1e-5f);
            #pragma unroll
            for (int u = 0; u < 16; ++u)
                v[u] = (v[u] - m2) * rs2 * fw[c0 + u] + fb[c0 + u];
        }
        #pragma unroll
        for (int u = 0; u < 16; u += 4)
            *(float4*)(Xs + rl * HD + c0 + u) =
                make_float4(v[u], v[u + 1], v[u + 2], v[u + 3]);
        __syncthreads();
    }

    float a00 = 0, a01 = 0, a02 = 0, a03 = 0;
    float a10 = 0, a11 = 0, a12 = 0, a13 = 0;

    int nch = Klen >> 6;
    float4 wreg[8];
    float4 xra, xrb, xrc;
    {
        int kg = kbase;
        #pragma unroll
        for (int p = 0; p < 8; ++p)
            wreg[p] = *(const float4*)(W + (size_t)(nb + scs + p * 16) * ldw + kg + q * 4);
        if (XMODE == XM_PLAIN) {
            xra = *(const float4*)(X + (size_t)(r0 + scs) * ldx + kg + q * 4);
        } else if (XMODE == XM_FQ) {
            xra = *(const float4*)(X + (size_t)((r0 + scs) % FH) * ldx + kg + q * 4);
        } else if (XMODE == XM_GELU) {
            const float* p0 = X + (size_t)(r0 + scs) * ldx + kg + q * 4;
            xra = *(const float4*)p0;
            xrb = *(const float4*)(p0 + gps);
            xrc = *(const float4*)(bo + kg + q * 4);
        }
    }

    for (int ch = 0; ch < nch; ++ch) {
        if (ch) __syncthreads();
        if (XMODE <= XM_FQ) {
            float4 xv;
            if (XMODE == XM_GELU) {
                xv.x = gelu_f(xra.x + xrb.x + xrc.x);
                xv.y = gelu_f(xra.y + xrb.y + xrc.y);
                xv.z = gelu_f(xra.z + xrb.z + xrc.z);
                xv.w = gelu_f(xra.w + xrb.w + xrc.w);
            } else {
                xv = xra;
            }
            *(float4*)&Xs[scs * 64 + q * 4] = xv;
        }
        #pragma unroll
        for (int p = 0; p < 8; ++p) {
            int cc = scs + p * 16;
            Wt[(q * 4 + 0) * 129 + cc] = wreg[p].x;
            Wt[(q * 4 + 1) * 129 + cc] = wreg[p].y;
            Wt[(q * 4 + 2) * 129 + cc] = wreg[p].z;
            Wt[(q * 4 + 3) * 129 + cc] = wreg[p].w;
        }
        __syncthreads();
        if (ch + 1 < nch) {
            int kg = kbase + (ch + 1) * 64;
            #pragma unroll
            for (int p = 0; p < 8; ++p)
                wreg[p] = *(const float4*)(W + (size_t)(nb + scs + p * 16) * ldw + kg + q * 4);
            if (XMODE == XM_PLAIN) {
                xra = *(const float4*)(X + (size_t)(r0 + scs) * ldx + kg + q * 4);
            } else if (XMODE == XM_FQ) {
                xra = *(const float4*)(X + (size_t)((r0 + scs) % FH) * ldx + kg + q * 4);
            } else if (XMODE == XM_GELU) {
                const float* p0 = X + (size_t)(r0 + scs) * ldx + kg + q * 4;
                xra = *(const float4*)p0;
                xrb = *(const float4*)(p0 + gps);
                xrc = *(const float4*)(bo + kg + q * 4);
            }
        }
        if (RT == 16) {
            const float* xr0 = &Xs[(rg * 2 + 0) * 64];
            const float* xr1 = &Xs[(rg * 2 + 1) * 64];
            #pragma unroll
            for (int k4 = 0; k4 < 16; ++k4) {
                float4 x0 = *(const float4*)(xr0 + k4 * 4);
                float4 x1 = *(const float4*)(xr1 + k4 * 4);
                const float* x0p = (const float*)&x0;
                const float* x1p = (const float*)&x1;
                #pragma unroll
                for (int i = 0; i < 4; ++i) {
                    const float* wrow = &Wt[(k4 * 4 + i) * 129 + c];
                    float w0 = wrow[0], w1 = wrow[32], w2 = wrow[64], w3 = wrow[96];
                    float xi0 = x0p[i], xi1 = x1p[i];
                    a00 = fmaf(xi0, w0, a00); a01 = fmaf(xi0, w1, a01);
                    a02 = fmaf(xi0, w2, a02); a03 = fmaf(xi0, w3, a03);
                    a10 = fmaf(xi1, w0, a10); a11 = fmaf(xi1, w1, a11);
                    a12 = fmaf(xi1, w2, a12); a13 = fmaf(xi1, w3, a13);
                }
            }
        } else {
            const float* xr0 = &Xs[rg * HD + kbase + ch * 64];
            #pragma unroll
            for (int k4 = 0; k4 < 16; ++k4) {
                float4 x0 = *(const float4*)(xr0 + k4 * 4);
                const float* x0p = (const float*)&x0;
                #pragma unroll
                for (int i = 0; i < 4; ++i) {
                    const float* wrow = &Wt[(k4 * 4 + i) * 129 + c];
                    float xi0 = x0p[i];
                    a00 = fmaf(xi0, wrow[0],  a00);
                    a01 = fmaf(xi0, wrow[32], a01);
                    a02 = fmaf(xi0, wrow[64], a02);
                    a03 = fmaf(xi0, wrow[96], a03);
                }
            }
        }
    }
    if (RT == 16) {
        float* yr = Yb + (size_t)(r0 + rg * 2) * ldy + nb + c;
        yr[0] = a00; yr[32] = a01; yr[64] = a02; yr[96] = a03;
        yr += ldy;
        yr[0] = a10; yr[32] = a11; yr[64] = a12; yr[96] = a13;
    } else {
        float* yr = Yb + (size_t)(r0 + rg) * ldy + nb + c;
        yr[0] = a00; yr[32] = a01; yr[64] = a02; yr[96] = a03;
    }
}

template <int XMODE>
__global__ __launch_bounds__(256) void k_gemm(
    const float* __restrict__ X, int ldx,
    const float* __restrict__ parts, int np, int pzstr,
    const float* __restrict__ bo,
    const float* __restrict__ lw, const float* __restrict__ lb,
    const float* __restrict__ fw, const float* __restrict__ fb,
    float* __restrict__ xout, int xmod, int gps,
    const float* __restrict__ W, int ldw,
    float* __restrict__ Y, int ldy, int zyoff, int Klen)
{
    __shared__ float lds[(XMODE >= XM_LN) ? 12352 : 9280];
    gemm_body<XMODE>(blockIdx.x, blockIdx.y, blockIdx.z, X, ldx, parts, np, pzstr,
                     bo, lw, lb, fw, fb, xout, xmod, gps, W, ldw, Y, ldy, zyoff,
                     Klen, lds);
}

// ---------------------------------------------------------------------------
// M = pe2^T @ [pred;ex]^T -> bf16 MFMA B-frags (R5-verified layout) + cb.
// R8: pred_w staged in LDS chunks; accumulate via ds_read_b128 broadcast
// (kills the s_load chain that made mprep a 50us straggler).
// ---------------------------------------------------------------------------
__device__ void mprep(int m, const float* __restrict__ pe2_w, const float* __restrict__ pe2_b,
                      const float* __restrict__ pred_w, const float* __restrict__ pred_b,
                      const float* __restrict__ ex_w, const float* __restrict__ ex_b,
                      unsigned short* __restrict__ Mbf, float* __restrict__ cb, float* lds)
{
    int t = threadIdx.x;
    if (m < 16) {
        int dl = t & 31, ec = t >> 5;        // 8 e-groups x 32 d-lanes
        int d = m * 32 + dl;
        float acc[27];
        #pragma unroll
        for (int k = 0; k < 27; ++k) acc[k] = 0.f;
        // group ec covers e in [ec*64, ec*64+64), processed as 2 x 32-e subchunks
        for (int sub = 0; sub < 2; ++sub) {
            __syncthreads();
            // stage pred chunk: lds[g*864 + k*32 + el] = W27[k][g*64 + sub*32 + el]
            for (int idx = t; idx < 1728; idx += 256) {
                int g = idx / 216, r = idx - g * 216;
                int k = r >> 3, f4 = (r & 7) * 4;
                int eoff = g * 64 + sub * 32 + f4;
                float4 pv = (k < 26) ? *(const float4*)(pred_w + k * HD + eoff)
                                     : *(const float4*)(ex_w + eoff);
                *(float4*)(lds + g * 864 + k * 32 + f4) = pv;
            }
            __syncthreads();
            int ebase = ec * 64 + sub * 32;
            const float* ps = lds + ec * 864;
            #pragma unroll 2
            for (int e4 = 0; e4 < 8; ++e4) {
                float w0 = pe2_w[(size_t)(ebase + e4 * 4 + 0) * HD + d];
                float w1 = pe2_w[(size_t)(ebase + e4 * 4 + 1) * HD + d];
                float w2 = pe2_w[(size_t)(ebase + e4 * 4 + 2) * HD + d];
                float w3 = pe2_w[(size_t)(ebase + e4 * 4 + 3) * HD + d];
                #pragma unroll
                for (int k = 0; k < 27; ++k) {
                    float4 pv = *(const float4*)(ps + k * 32 + e4 * 4);  // broadcast
                    acc[k] += w0 * pv.x + w1 * pv.y + w2 * pv.z + w3 * pv.w;
                }
            }
        }
        __syncthreads();
        #pragma unroll
        for (int k = 0; k < 27; ++k) lds[(ec * 32 + dl) * 27 + k] = acc[k];
        __syncthreads();
        for (int idx = t; idx < 1024; idx += 256) {
            int dl2 = idx >> 5, k = idx & 31;
            float s = 0.f;
            if (k < 27) {
                #pragma unroll
                for (int e = 0; e < 8; ++e) s += lds[(e * 32 + dl2) * 27 + k];
            }
            int quad = dl2 >> 3, j = dl2 & 7;
            int nt = k >> 4, n15 = k & 15;
            int lane = quad * 16 + n15;
            Mbf[((size_t)(m * 2 + nt) * 64 + lane) * 8 + j] = f2bf(s);
        }
    } else {
        int g = t >> 3, li = t & 7;
        if (g < 27) {
            const float* wo = (g < 26) ? (pred_w + g * HD) : ex_w;
            float a = 0.f;
            for (int e = li; e < HD; e += 8) a += pe2_b[e] * wo[e];
            a += __shfl_down(a, 4, 8);
            a += __shfl_down(a, 2, 8);
            a += __shfl_down(a, 1, 8);
            if (li == 0) cb[g] = a + ((g < 26) ? pred_b[g] : ex_b[0]);
        }
    }
}

// ---------------------------------------------------------------------------
// Merged prep: mprep [0,17) | SO [17,337) | CA-KV [337,657) | QKV-l0 [657,897).
// ---------------------------------------------------------------------------
__global__ __launch_bounds__(256) void k_prep(
    const float* __restrict__ objf, const float* __restrict__ temporal,
    const float* __restrict__ fq,
    const float* __restrict__ pe1_w, const float* __restrict__ ca_in_w,
    const float* __restrict__ sa_in_w,
    const float* __restrict__ pe2_w, const float* __restrict__ pe2_b,
    const float* __restrict__ pred_w, const float* __restrict__ pred_b,
    const float* __restrict__ ex_w, const float* __restrict__ ex_b,
    float* __restrict__ SOp, float* __restrict__ kvb,
    float* __restrict__ qkvp,
    unsigned short* __restrict__ Mbf, float* __restrict__ cb)
{
    __shared__ float lds[9280];
    int blk = blockIdx.x;
    if (blk < 17) {
        mprep(blk, pe2_w, pe2_b, pred_w, pred_b, ex_w, ex_b, Mbf, cb, lds);
    } else if (blk < 337) {
        int s = blk - 17;
        int zw = s & 1, zk = (s >> 1) & 1, ct = (s >> 2) & 3, y = s >> 4;
        gemm_body<XM_PLAIN>(ct, y, zk, objf, HD, nullptr, 0, 0,
                            nullptr, nullptr, nullptr, nullptr, nullptr,
                            nullptr, 0, 0,
                            pe1_w + zw * 512, 1536,
                            SOp + zw * 512, 1024, 327680, 256, lds);
    } else if (blk < 657) {
        int s = blk - 337;
        int ct = s & 7, l = (s >> 3) & 1, zk = (s >> 4) & 1, y = s >> 5;
        gemm_body<XM_PLAIN>(ct, y, zk, temporal, HD, nullptr, 0, 0,
                            nullptr, nullptr, nullptr, nullptr, nullptr,
                            nullptr, 0, 0,
                            ca_in_w + (size_t)(l * 1536 + 512) * HD, HD,
                            kvb + (size_t)((zk * 2 + l) * 160) * 1024, 1024, 0, 256, lds);
    } else {
        int s = blk - 657;
        int x = s % 12, y = (s / 12) % 5, z = s / 60;
        gemm_body<XM_FQ>(x, y, z, fq, HD, nullptr, 0, 0,
                         nullptr, nullptr, nullptr, nullptr, nullptr,
                         nullptr, 0, 0,
                         sa_in_w, HD, qkvp, 1536, 122880, 128, lds);
    }
}

// ---------------------------------------------------------------------------
// Fused SA + out-proj, head-sliced (heads {2zk,2zk+1}). 256 blocks.
// ---------------------------------------------------------------------------
__global__ __launch_bounds__(256) void k_attnsa_proj(
    int l, const float* __restrict__ qkvp, const float* __restrict__ in_b,
    const float* __restrict__ Wout, float* __restrict__ yp)
{
    __shared__ float lds[8896];
    int bi = blockIdx.x;
    int b = bi >> 4, ct = (bi >> 2) & 3, zk = bi & 3;
    int t = threadIdx.x;
    float* qkv = lds;          // [3][5][128]
    float* sc  = lds + 1920;   // 50
    float* aw  = lds + 1984;   // 50
    float* ao  = lds + 8256;   // [5][128]
    float* Wt  = lds;          // proj phase (attn scratch dead)
    int col0 = zk * 128;
    int c = t & 31, rg = t >> 5, scs = t >> 4, q = t & 15;
    int nb = ct * 128;

    float4 wreg[8];
    #pragma unroll
    for (int p = 0; p < 8; ++p)
        wreg[p] = *(const float4*)(Wout + (size_t)(nb + scs + p * 16) * HD + col0 + q * 4);

    for (int idx = t; idx < 480; idx += 256) {
        int m = idx / 160, r = idx - m * 160;
        int tok = r >> 5, c4 = (r & 31) * 4;
        int col = m * HD + col0 + c4;
        size_t o = (size_t)(b * FH + tok) * 1536 + col;
        float4 v = *(const float4*)(in_b + l * 1536 + col);
        #pragma unroll
        for (int z = 0; z < 4; ++z) {
            float4 p = *(const float4*)(qkvp + (size_t)z * 122880 + o);
            v.x += p.x; v.y += p.y; v.z += p.z; v.w += p.w;
        }
        *(float4*)(qkv + (m * FH + tok) * 128 + c4) = v;
    }
    __syncthreads();
    if (t < 50) {
        int hh = t / 25, r = t - hh * 25, tq = r / 5, tu = r % 5;
        float s = 0;
        for (int d = 0; d < 64; ++d)
            s += qkv[tq * 128 + hh * 64 + d] * qkv[(FH + tu) * 128 + hh * 64 + d];
        sc[t] = s * 0.125f;
    }
    __syncthreads();
    if (t < 10) {
        int base = (t / 5) * 25 + (t % 5) * 5;
        float mx = -1e30f;
        for (int u = 0; u < 5; ++u) mx = fmaxf(mx, sc[base + u]);
        float e[5], sm = 0;
        for (int u = 0; u < 5; ++u) { e[u] = expf(sc[base + u] - mx); sm += e[u]; }
        for (int u = 0; u < 5; ++u) aw[base + u] = e[u] / sm;
    }
    __syncthreads();
    for (int idx = t; idx < 640; idx += 256) {
        int tok = idx >> 7, cc = idx & 127, hh = cc >> 6;
        float s = 0;
        #pragma unroll
        for (int u = 0; u < 5; ++u)
            s += aw[hh * 25 + tok * 5 + u] * qkv[(2 * FH + u) * 128 + cc];
        ao[tok * 128 + cc] = s;
    }
    __syncthreads();

    float a0 = 0, a1 = 0, a2 = 0, a3 = 0;
    for (int ch = 0; ch < 2; ++ch) {
        if (ch) __syncthreads();
        #pragma unroll
        for (int p = 0; p < 8; ++p) {
            int cc = scs + p * 16;
            Wt[(q * 4 + 0) * 129 + cc] = wreg[p].x;
            Wt[(q * 4 + 1) * 129 + cc] = wreg[p].y;
            Wt[(q * 4 + 2) * 129 + cc] = wreg[p].z;
            Wt[(q * 4 + 3) * 129 + cc] = wreg[p].w;
        }
        __syncthreads();
        if (ch == 0) {
            #pragma unroll
            for (int p = 0; p < 8; ++p)
                wreg[p] = *(const float4*)(Wout + (size_t)(nb + scs + p * 16) * HD + col0 + 64 + q * 4);
        }
        if (rg < FH) {
            const float* xr = ao + rg * 128 + ch * 64;
            #pragma unroll
            for (int k4 = 0; k4 < 16; ++k4) {
                float4 xv = *(const float4*)(xr + k4 * 4);
                #pragma unroll
                for (int i = 0; i < 4; ++i) {
                    const float* wr = &Wt[(k4 * 4 + i) * 129 + c];
                    float x = ((const float*)&xv)[i];
                    a0 = fmaf(x, wr[0],  a0); a1 = fmaf(x, wr[32], a1);
                    a2 = fmaf(x, wr[64], a2); a3 = fmaf(x, wr[96], a3);
                }
            }
        }
    }
    if (rg < FH) {
        float* yr = yp + (size_t)zk * 40960 + (size_t)(b * FH + rg) * HD + nb + c;
        yr[0] = a0; yr[32] = a1; yr[64] = a2; yr[96] = a3;
    }
}

// ---------------------------------------------------------------------------
// Fused CA + out-proj, head-sliced. Block (b, ct, zk): 256 blocks.
// qp now has 8 k-split partials.
// ---------------------------------------------------------------------------
__global__ __launch_bounds__(256) void k_attnca_proj(
    int l, const float* __restrict__ qp, const float* __restrict__ kvb,
    const float* __restrict__ in_b, const float* __restrict__ Wout,
    float* __restrict__ yp)
{
    __shared__ float lds[8896];
    int bi = blockIdx.x;
    int b = bi >> 4, ct = (bi >> 2) & 3, zk = bi & 3;
    int t = threadIdx.x;
    float* qs = lds;            // [5][128]
    float* kl = lds + 640;      // [10][128]
    float* vl = lds + 1920;     // [10][128]
    float* sc = lds + 3200;     // 100
    float* aw = lds + 3328;     // 100
    float* ao = lds + 8256;     // [5][128]
    float* Wt = lds;            // proj phase
    const float* bb = in_b + l * 1536;
    int col0 = zk * 128;
    int c = t & 31, rg = t >> 5, scs = t >> 4, q = t & 15;
    int nb = ct * 128;

    float4 wreg[8];
    #pragma unroll
    for (int p = 0; p < 8; ++p)
        wreg[p] = *(const float4*)(Wout + (size_t)(nb + scs + p * 16) * HD + col0 + q * 4);

    if (t < 160) {
        int tok = t >> 5, c4 = (t & 31) * 4;
        size_t o = (size_t)(b * FH + tok) * HD + col0 + c4;
        float4 v = *(const float4*)(bb + col0 + c4);
        #pragma unroll
        for (int z = 0; z < 8; ++z) {
            float4 p = *(const float4*)(qp + (size_t)z * 40960 + o);
            v.x += p.x; v.y += p.y; v.z += p.z; v.w += p.w;
        }
        *(float4*)(qs + tok * 128 + c4) = v;
    }
    for (int idx = t; idx < 320; idx += 256) {
        int u = idx >> 5, c4 = (idx & 31) * 4;
        size_t base = (size_t)(l * 160 + b * TM + u) * 1024;
        float4 k0 = *(const float4*)(kvb + base + col0 + c4);
        float4 k1 = *(const float4*)(kvb + 327680 + base + col0 + c4);
        float4 bk = *(const float4*)(bb + 512 + col0 + c4);
        *(float4*)(kl + u * 128 + c4) =
            make_float4(k0.x + k1.x + bk.x, k0.y + k1.y + bk.y,
                        k0.z + k1.z + bk.z, k0.w + k1.w + bk.w);
        float4 v0 = *(const float4*)(kvb + base + 512 + col0 + c4);
        float4 v1 = *(const float4*)(kvb + 327680 + base + 512 + col0 + c4);
        float4 bv = *(const float4*)(bb + 1024 + col0 + c4);
        *(float4*)(vl + u * 128 + c4) =
            make_float4(v0.x + v1.x + bv.x, v0.y + v1.y + bv.y,
                        v0.z + v1.z + bv.z, v0.w + v1.w + bv.w);
    }
    __syncthreads();
    if (t < 100) {
        int hh = t / 50, r = t - hh * 50, tq = r / 10, tu = r % 10;
        float s = 0;
        for (int d = 0; d < 64; ++d)
            s += qs[tq * 128 + hh * 64 + d] * kl[tu * 128 + hh * 64 + d];
        sc[t] = s * 0.125f;
    }
    __syncthreads();
    if (t < 10) {
        int base = (t / 5) * 50 + (t % 5) * 10;
        float mx = -1e30f;
        for (int u = 0; u < TM; ++u) mx = fmaxf(mx, sc[base + u]);
        float e[TM], sm = 0;
        for (int u = 0; u < TM; ++u) { e[u] = expf(sc[base + u] - mx); sm += e[u]; }
        for (int u = 0; u < TM; ++u) aw[base + u] = e[u] / sm;
    }
    __syncthreads();
    for (int idx = t; idx < 640; idx += 256) {
        int tok = idx >> 7, cc = idx & 127, hh = cc >> 6;
        float s = 0;
        #pragma unroll
        for (int u = 0; u < TM; ++u)
            s += aw[hh * 50 + tok * 10 + u] * vl[u * 128 + cc];
        ao[tok * 128 + cc] = s;
    }
    __syncthreads();

    float a0 = 0, a1 = 0, a2 = 0, a3 = 0;
    for (int ch = 0; ch < 2; ++ch) {
        if (ch) __syncthreads();
        #pragma unroll
        for (int p = 0; p < 8; ++p) {
            int cc = scs + p * 16;
            Wt[(q * 4 + 0) * 129 + cc] = wreg[p].x;
            Wt[(q * 4 + 1) * 129 + cc] = wreg[p].y;
            Wt[(q * 4 + 2) * 129 + cc] = wreg[p].z;
            Wt[(q * 4 + 3) * 129 + cc] = wreg[p].w;
        }
        __syncthreads();
        if (ch == 0) {
            #pragma unroll
            for (int p = 0; p < 8; ++p)
                wreg[p] = *(const float4*)(Wout + (size_t)(nb + scs + p * 16) * HD + col0 + 64 + q * 4);
        }
        if (rg < FH) {
            const float* xr = ao + rg * 128 + ch * 64;
            #pragma unroll
            for (int k4 = 0; k4 < 16; ++k4) {
                float4 xv = *(const float4*)(xr + k4 * 4);
                #pragma unroll
                for (int i = 0; i < 4; ++i) {
                    const float* wr = &Wt[(k4 * 4 + i) * 129 + c];
                    float x = ((const float*)&xv)[i];
                    a0 = fmaf(x, wr[0],  a0); a1 = fmaf(x, wr[32], a1);
                    a2 = fmaf(x, wr[64], a2); a3 = fmaf(x, wr[96], a3);
                }
            }
        }
    }
    if (rg < FH) {
        float* yr = yp + (size_t)zk * 40960 + (size_t)(b * FH + rg) * HD + nb + c;
        yr[0] = a0; yr[32] = a1; yr[64] = a2; yr[96] = a3;
    }
}

// ---------------------------------------------------------------------------
// Pair head via MFMA (R5-verified layouts). grid = 240. cpb now 8 partials.
// ---------------------------------------------------------------------------
__global__ __launch_bounds__(256) void k_pair(
    const float* __restrict__ SOp, const float* __restrict__ cpb,
    const float* __restrict__ pe1_b,
    const unsigned short* __restrict__ Mbf, const float* __restrict__ cb,
    float* __restrict__ out)
{
    __shared__ float lds[14964];
    int blk = blockIdx.x;
    int third = blk % 3, bf = blk / 3;
    int b = bf / FH, f = bf % FH;
    int t = threadIdx.x;
    int wv = t >> 6, lane = t & 63;
    int quad = lane >> 4, n15 = lane & 15;
    int i0 = (third == 0) ? 0 : (third == 1 ? 6 : 13);

    for (int idx = t; idx < 29 * 128; idx += 256) {
        int row = idx >> 7, c4 = (idx & 127) << 2;
        float4 v;
        if (row < 8) {
            int i = i0 + row; if (i > 19) i = 19;
            size_t o = (size_t)(b * NO + i) * 1024 + c4;
            float4 p0 = *(const float4*)(SOp + o);
            float4 p1 = *(const float4*)(SOp + 327680 + o);
            v = make_float4(p0.x + p1.x, p0.y + p1.y, p0.z + p1.z, p0.w + p1.w);
        } else if (row < 28) {
            int j = row - 8;
            size_t o = (size_t)(b * NO + j) * 1024 + 512 + c4;
            float4 p0 = *(const float4*)(SOp + o);
            float4 p1 = *(const float4*)(SOp + 327680 + o);
            v = make_float4(p0.x + p1.x, p0.y + p1.y, p0.z + p1.z, p0.w + p1.w);
        } else {
            size_t o = (size_t)(b * FH + f) * HD + c4;
            float4 s = *(const float4*)(cpb + o);
            #pragma unroll
            for (int z = 1; z < 8; ++z) {
                float4 p = *(const float4*)(cpb + (size_t)z * 40960 + o);
                s.x += p.x; s.y += p.y; s.z += p.z; s.w += p.w;
            }
            float4 pb = *(const float4*)(pe1_b + c4);
            v = make_float4(s.x + pb.x, s.y + pb.y, s.z + pb.z, s.w + pb.w);
        }
        *(float4*)(lds + row * 516 + c4) = v;
    }
    __syncthreads();

    floatx4 acc00 = {0,0,0,0}, acc01 = {0,0,0,0}, acc10 = {0,0,0,0}, acc11 = {0,0,0,0};
    for (int ks = 0; ks < 16; ++ks) {
        bf16x8 b0 = *(const bf16x8*)(Mbf + ((size_t)(ks * 2 + 0) * 64 + lane) * 8);
        bf16x8 b1 = *(const bf16x8*)(Mbf + ((size_t)(ks * 2 + 1) * 64 + lane) * 8);
        #pragma unroll
        for (int mt = 0; mt < 2; ++mt) {
            int p = third * 128 + wv * 32 + mt * 16 + n15;
            bf16x8 afr = {0, 0, 0, 0, 0, 0, 0, 0};
            if (p < NP) {
                int i = p / 19, j0 = p % 19;
                int j = j0 + (j0 >= i ? 1 : 0);
                int dof = ks * 32 + quad * 8;
                const float* Sr = lds + (i - i0) * 516 + dof;
                const float* Or = lds + (8 + j) * 516 + dof;
                const float* Cr = lds + 28 * 516 + dof;
                float4 sa = *(const float4*)Sr, sb = *(const float4*)(Sr + 4);
                float4 oa = *(const float4*)Or, ob = *(const float4*)(Or + 4);
                float4 ca = *(const float4*)Cr, cc = *(const float4*)(Cr + 4);
                union { unsigned short u[8]; bf16x8 v8; } pk;
                pk.u[0] = f2bf(gelu_f(sa.x + oa.x + ca.x));
                pk.u[1] = f2bf(gelu_f(sa.y + oa.y + ca.y));
                pk.u[2] = f2bf(gelu_f(sa.z + oa.z + ca.z));
                pk.u[3] = f2bf(gelu_f(sa.w + oa.w + ca.w));
                pk.u[4] = f2bf(gelu_f(sb.x + ob.x + cc.x));
                pk.u[5] = f2bf(gelu_f(sb.y + ob.y + cc.y));
                pk.u[6] = f2bf(gelu_f(sb.z + ob.z + cc.z));
                pk.u[7] = f2bf(gelu_f(sb.w + ob.w + cc.w));
                afr = pk.v8;
            }
            if (mt == 0) {
                acc00 = __builtin_amdgcn_mfma_f32_16x16x32_bf16(afr, b0, acc00, 0, 0, 0);
                acc01 = __builtin_amdgcn_mfma_f32_16x16x32_bf16(afr, b1, acc01, 0, 0, 0);
            } else {
                acc10 = __builtin_amdgcn_mfma_f32_16x16x32_bf16(afr, b0, acc10, 0, 0, 0);
                acc11 = __builtin_amdgcn_mfma_f32_16x16x32_bf16(afr, b1, acc11, 0, 0, 0);
            }
        }
    }
    int pbase = (b * FH + f) * NP;
    #pragma unroll
    for (int mt = 0; mt < 2; ++mt) {
        #pragma unroll
        for (int nt = 0; nt < 2; ++nt) {
            floatx4 a = (mt == 0) ? (nt == 0 ? acc00 : acc01)
                                  : (nt == 0 ? acc10 : acc11);
            int n = nt * 16 + n15;
            #pragma unroll
            for (int reg = 0; reg < 4; ++reg) {
                int p = third * 128 + wv * 32 + mt * 16 + quad * 4 + reg;
                if (p < NP && n < 27) {
                    float vout = a[reg] + cb[n];
                    if (n < 26) out[(size_t)(pbase + p) * 26 + n] = vout;
                    else        out[PRED_N + pbase + p] = vout;
                }
            }
        }
    }
}

// ---------------------------------------------------------------------------
extern "C" void kernel_launch(void* const* d_in, const int* in_sizes, int n_in,
                              void* d_out, int out_size, void* d_ws, size_t ws_size,
                              hipStream_t stream) {
    const float* temporal = (const float*)d_in[0];
    const float* objf     = (const float*)d_in[1];
    const float* fq       = (const float*)d_in[2];
    const float* sa_in_w  = (const float*)d_in[3];
    const float* sa_in_b  = (const float*)d_in[4];
    const float* sa_out_w = (const float*)d_in[5];
    const float* sa_out_b = (const float*)d_in[6];
    const float* ca_in_w  = (const float*)d_in[7];
    const float* ca_in_b  = (const float*)d_in[8];
    const float* ca_out_w = (const float*)d_in[9];
    const float* ca_out_b = (const float*)d_in[10];
    const float* ff1_w    = (const float*)d_in[11];
    const float* ff1_b    = (const float*)d_in[12];
    const float* ff2_w    = (const float*)d_in[13];
    const float* ff2_b    = (const float*)d_in[14];
    const float* n1_w     = (const float*)d_in[15];
    const float* n1_b     = (const float*)d_in[16];
    const float* n2_w     = (const float*)d_in[17];
    const float* n2_b     = (const float*)d_in[18];
    const float* n3_w     = (const float*)d_in[19];
    const float* n3_b     = (const float*)d_in[20];
    const float* norm_w   = (const float*)d_in[21];
    const float* norm_b   = (const float*)d_in[22];
    const float* pe1_w    = (const float*)d_in[23];
    const float* pe1_b    = (const float*)d_in[24];
    const float* pe2_w    = (const float*)d_in[25];
    const float* pe2_b    = (const float*)d_in[26];
    const float* pred_w   = (const float*)d_in[27];
    const float* pred_b   = (const float*)d_in[28];
    const float* ex_w     = (const float*)d_in[29];
    const float* ex_b     = (const float*)d_in[30];

    // ---- workspace (floats), total 2,916,384 ~= 11.7 MB (proven size) ----
    // big is time-shared: qkvp (4x122880) / qp (8x40960) / ffp (2x163840)
    float* ws   = (float*)d_ws;
    float* x1   = ws;                    // 40960
    float* x2   = ws + 40960;            // 40960
    float* x3   = ws + 81920;            // 40960
    float* big  = ws + 122880;           // 491520
    float* yp   = ws + 614400;           // 16 x 40960 = 655360
    float* kvb  = ws + 1269760;          // [zk2][l2][160][1024] = 655360
    float* SOp  = ws + 1925120;          // [zk2][320][1024] = 655360
    float* cpb  = ws + 2580480;          // 8 x 40960 = 327680
    unsigned short* Mbf = (unsigned short*)(ws + 2908160);  // 16384 ushort
    float* cb   = ws + 2916352;          // 32
    float* out  = (float*)d_out;
    float* qkvp = big;
    float* qp   = big;
    float* ffp  = big;

    k_prep<<<897, 256, 0, stream>>>(objf, temporal, fq, pe1_w, ca_in_w, sa_in_w,
                                    pe2_w, pe2_b, pred_w, pred_b, ex_w, ex_b,
                                    SOp, kvb, qkvp, Mbf, cb);
    for (int l = 0; l < 2; ++l) {
        if (l == 1) {
            // LN3(l0) prologue: x3 = LN(x2 + 16 FF2 partials + ff2_b0; n3_0)
            k_gemm<XM_LN><<<dim3(12, 10, 4), 256, 0, stream>>>(
                x2, HD, yp, 16, 40960, ff2_b, n3_w, n3_b,
                nullptr, nullptr, x3, 0, 0,
                sa_in_w + 786432, HD, qkvp, 1536, 122880, 128);
        }
        k_attnsa_proj<<<256, 256, 0, stream>>>(l, qkvp, sa_in_b,
                                               sa_out_w + (size_t)l * 262144, yp);
        // LN1 prologue + CA-Q (z=8, Klen 64)
        k_gemm<XM_LN><<<dim3(4, 10, 8), 256, 0, stream>>>(
            (l == 0 ? fq : x3), HD, yp, 4, 40960,
            sa_out_b + l * HD, n1_w + l * HD, n1_b + l * HD,
            nullptr, nullptr, x1, (l == 0 ? FH : 0), 0,
            ca_in_w + (size_t)l * 786432, HD, qp, HD, 40960, 64);
        k_attnca_proj<<<256, 256, 0, stream>>>(l, qp, kvb, ca_in_b,
                                               ca_out_w + (size_t)l * 262144, yp);
        // LN2 prologue + FF1 (z=2)
        k_gemm<XM_LN><<<dim3(16, 10, 2), 256, 0, stream>>>(
            x1, HD, yp, 4, 40960,
            ca_out_b + l * HD, n2_w + l * HD, n2_b + l * HD,
            nullptr, nullptr, x2, 0, 0,
            ff1_w + (size_t)l * 1048576, HD, ffp, FFD, 163840, 256);
        // FF2 with gelu-combine staging (2 FF1 partials), z=16, Klen 128
        k_gemm<XM_GELU><<<dim3(4, 5, 16), 256, 0, stream>>>(
            ffp, FFD, nullptr, 0, 0, ff1_b + l * FFD,
            nullptr, nullptr, nullptr, nullptr, nullptr, 0, 163840,
            ff2_w + (size_t)l * 1048576, FFD, yp, HD, 40960, 128);
    }
    // LN3(l1)+final LN prologue, then ctx projection (z=8, Klen 64)
    k_gemm<XM_LN2><<<dim3(4, 10, 8), 256, 0, stream>>>(
        x2, HD, yp, 16, 40960, ff2_b + HD, n3_w + HD, n3_b + HD,
        norm_w, norm_b, nullptr, 0, 0,
        pe1_w + 1024, 1536, cpb, HD, 40960, 64);
    k_pair<<<240, 256, 0, stream>>>(SOp, cpb, pe1_b, Mbf, cb, out);
}